// Round 5
// baseline (658.329 us; speedup 1.0000x reference)
//
#include <hip/hip_runtime.h>

// SparseGraphConv: y = W @ concat([x, A1x, A1^2 x, A2 x, A2^2 x]) + b
// B=16, C=64, N=2048, T=12, C_OUT=64.
//
//   1. cvt_a:   A1,A2 f32 -> bf16 rows of Astack[8192,2048] (+ transposed copies)
//   2. gemm128(z=2): A1^2, A2^2 -> remaining Astack rows
//   3. pack_x:  x[b,c,n,t] f32 -> XtT[(b*12+t)*64+c][n] bf16
//   4. gemm256: Y[8192, 12288] = Astack @ XtT^T  -- 256^2, R2/R4 sync skeleton,
//               v_mfma_f32_32x32x16_bf16 math (2495 TF pipe vs 2176 for 16x16)
//   5. conv:    per node n: y[b,o,n,t] = bias[o] + sum_k W_k @ h_k

typedef __attribute__((ext_vector_type(8))) __bf16 bf16x8;
typedef __attribute__((ext_vector_type(4))) float f32x4;
typedef __attribute__((ext_vector_type(16))) float f32x16;
typedef __attribute__((ext_vector_type(8))) unsigned short u16x8;
typedef unsigned short u16;
typedef unsigned int u32;

__device__ __forceinline__ u16 f2bf(float f) {
    u32 u = __float_as_uint(f);
    u32 r = u + 0x7FFFu + ((u >> 16) & 1u);   // round-to-nearest-even
    return (u16)(r >> 16);
}

__device__ __forceinline__ void gload16(const void* g, void* l) {
    __builtin_amdgcn_global_load_lds((const __attribute__((address_space(1))) void*)g,
                                     (__attribute__((address_space(3))) void*)l, 16, 0, 0);
}

// ---------------------------------------------------------------------------
__global__ __launch_bounds__(256)
void cvt_w_kernel(const float* __restrict__ W, u16* __restrict__ wbf) {
    int i = blockIdx.x * 256 + threadIdx.x;
    if (i < 5 * 64 * 64) {
        int c = i & 63;
        int o = (i >> 6) & 63;
        int k = i >> 12;
        wbf[i] = f2bf(W[o * 320 + k * 64 + c]);
    }
}

// ---------------------------------------------------------------------------
__global__ __launch_bounds__(256)
void cvt_a_kernel(const float* __restrict__ A1, const float* __restrict__ A2,
                  u16* __restrict__ astack, u16* __restrict__ a1t, u16* __restrict__ a2t) {
    __shared__ float lt[64][65];
    int bid = blockIdx.x;
    int mat = bid >> 10;
    int ti = bid & 1023;
    int tr = (ti >> 5) << 6;
    int tc = (ti & 31) << 6;
    const float* src = mat ? A2 : A1;
    u16* dstA = astack + (size_t)(mat ? 4096 : 0) * 2048;
    u16* dstT = mat ? a2t : a1t;
    int tid = threadIdx.x;
    int rr = tid >> 4;
    int cc = (tid & 15) << 2;
#pragma unroll
    for (int p = 0; p < 4; ++p) {
        int row = p * 16 + rr;
        float4 v = *(const float4*)&src[(size_t)(tr + row) * 2048 + tc + cc];
        ushort4 o;
        o.x = f2bf(v.x); o.y = f2bf(v.y); o.z = f2bf(v.z); o.w = f2bf(v.w);
        *(ushort4*)&dstA[(size_t)(tr + row) * 2048 + tc + cc] = o;
        lt[row][cc + 0] = v.x; lt[row][cc + 1] = v.y;
        lt[row][cc + 2] = v.z; lt[row][cc + 3] = v.w;
    }
    __syncthreads();
#pragma unroll
    for (int p = 0; p < 4; ++p) {
        int row = p * 16 + rr;
        ushort4 o;
        o.x = f2bf(lt[cc + 0][row]); o.y = f2bf(lt[cc + 1][row]);
        o.z = f2bf(lt[cc + 2][row]); o.w = f2bf(lt[cc + 3][row]);
        *(ushort4*)&dstT[(size_t)(tc + row) * 2048 + tr + cc] = o;
    }
}

// ---------------------------------------------------------------------------
__global__ __launch_bounds__(256)
void pack_x_kernel(const float* __restrict__ x, u16* __restrict__ XtT, int b0, int Gb) {
    int tid = blockIdx.x * 256 + threadIdx.x;
    int n = tid & 2047;
    int bc = tid >> 11;
    int c = bc & 63;
    int bl = bc >> 6;
    const float* src = x + ((size_t)((b0 + bl) * 64 + c) * 2048 + n) * 12;
    float4 v0 = *(const float4*)(src + 0);
    float4 v1 = *(const float4*)(src + 4);
    float4 v2 = *(const float4*)(src + 8);
    float vv[12];
    *(float4*)&vv[0] = v0; *(float4*)&vv[4] = v1; *(float4*)&vv[8] = v2;
    u16* dst = XtT + (size_t)(bl * 12 * 64 + c) * 2048 + n;
#pragma unroll
    for (int t = 0; t < 12; ++t)
        dst[(size_t)t * 64 * 2048] = f2bf(vv[t]);
}

// ---------------------------------------------------------------------------
// 128^2-tile GEMM (kept for the small A^2 GEMMs).
__global__ __launch_bounds__(256, 2)
void gemm_bt_kernel(const u16* __restrict__ A0, const u16* __restrict__ B0, u16* __restrict__ C0,
                    const u16* __restrict__ A1p, const u16* __restrict__ B1p, u16* __restrict__ C1p,
                    int K, int lda, int ldb, int ldc) {
    const u16* A  = blockIdx.z ? A1p : A0;
    const u16* BT = blockIdx.z ? B1p : B0;
    u16* C        = blockIdx.z ? C1p : C0;

    __shared__ u16 lA[128 * 64];
    __shared__ u16 lB[128 * 64];

    int gx = gridDim.x;
    int nwg = gx * gridDim.y;
    int orig = blockIdx.y * gx + blockIdx.x;
    int swz = (orig & 7) * (nwg >> 3) + (orig >> 3);
    int by = swz / gx, bx = swz - by * gx;

    const int m0 = by * 128, n0 = bx * 128;
    const int tid = threadIdx.x;
    const int w = tid >> 6, l = tid & 63;
    const int wr = w >> 1, wc = w & 1;

    f32x4 acc[4][4] = {};

    const int srow = l >> 3;
    const int scol = ((l & 7) ^ srow) * 8;

    for (int kt = 0; kt < K; kt += 64) {
#pragma unroll
        for (int r = 0; r < 4; ++r) {
            int s = w * 4 + r;
            int row = s * 8 + srow;
            gload16(A + (size_t)(m0 + row) * lda + kt + scol, &lA[s * 512]);
        }
#pragma unroll
        for (int r = 0; r < 4; ++r) {
            int s = w * 4 + r;
            int row = s * 8 + srow;
            gload16(BT + (size_t)(n0 + row) * ldb + kt + scol, &lB[s * 512]);
        }
        __syncthreads();
#pragma unroll
        for (int kk = 0; kk < 2; ++kk) {
            bf16x8 af[4], bfr[4];
            const int cg = ((kk * 4 + (l >> 4)) ^ (l & 7)) * 8;
#pragma unroll
            for (int i = 0; i < 4; ++i)
                af[i] = *(const bf16x8*)&lA[(wr * 64 + i * 16 + (l & 15)) * 64 + cg];
#pragma unroll
            for (int j = 0; j < 4; ++j)
                bfr[j] = *(const bf16x8*)&lB[(wc * 64 + j * 16 + (l & 15)) * 64 + cg];
#pragma unroll
            for (int i = 0; i < 4; ++i)
#pragma unroll
                for (int j = 0; j < 4; ++j)
                    acc[i][j] = __builtin_amdgcn_mfma_f32_16x16x32_bf16(af[i], bfr[j], acc[i][j], 0, 0, 0);
        }
        __syncthreads();
    }

    const int lr = (l >> 4) * 4, lc = l & 15;
#pragma unroll
    for (int i = 0; i < 4; ++i) {
        int row = m0 + wr * 64 + i * 16 + lr;
#pragma unroll
        for (int j = 0; j < 4; ++j) {
            int col = n0 + wc * 64 + j * 16 + lc;
            u16* p = C + (size_t)row * ldc + col;
#pragma unroll
            for (int q = 0; q < 4; ++q)
                p[(size_t)q * ldc] = f2bf(acc[i][j][q]);
        }
    }
}

// ---------------------------------------------------------------------------
// 256^2-tile GEMM: R4's verified sync skeleton; math switched to
// v_mfma_f32_32x32x16_bf16 (8 MFMA/phase, 2 dep-chains of 4).
// Per-wave output 128x64: qm in {0,1} (64 rows), qn in {0,1} (32 cols);
// per quadrant: 2 m-tiles (32 rows) x 1 n-tile x 4 ksteps (K=16 each).
// A-frag: lane row = l&31, k-group = (l>>5); B-frag: lane col = l&31.
// C/D: col = lane&31, row = (reg&3) + 8*(reg>>2) + 4*(lane>>5)  [m74/m101].
//
// Stage placement (= R4): P1: B1(t+1)->other buf; P2: A0(t+2)->cur A;
// P3: B0(t+2)->cur B; P4: A1(t+2)->cur A; boundary vmcnt(6)+barrier.
__device__ __forceinline__ void stage_half256(const u16* __restrict__ src, int ld,
                                              u16* lds, int kt, int tid) {
    int w8 = (tid >> 6) << 3;
    int l = tid & 63;
    int r = l >> 3;
#pragma unroll
    for (int iss = 0; iss < 2; ++iss) {
        int R = iss * 64 + w8 + r;
        gload16(src + (size_t)R * ld + kt + (((l & 7) ^ r) << 3),
                lds + (size_t)(iss * 64 + w8) * 64);
    }
}

__device__ __forceinline__ void tile_body256(
        u16* __restrict__ cA, u16* __restrict__ cB, u16* __restrict__ oB,
        const u16* __restrict__ A, const u16* __restrict__ BT,
        int lda, int ldb, int m0, int n0, int kt1, int kt2, bool s1, bool s2,
        int tid, f32x16 (&acc)[2][2][2]) {
    const int l = tid & 63;
    const int wr = (tid >> 6) >> 2, wc = (tid >> 6) & 3;
    const int lm = l & 31, hi = l >> 5;

    bf16x8 af[4][2], bq0[4], bq1[4];

    // ---- P1: read A(qm0) + B(qn0) frags; stage B1(t+1) -> other buf ----
#pragma unroll
    for (int ks = 0; ks < 4; ++ks) {
#pragma unroll
        for (int i = 0; i < 2; ++i) {
            int r = wr * 128 + i * 32 + lm;
            int g = (ks * 2 + hi) ^ (r & 7);
            af[ks][i] = *(const bf16x8*)&cA[(size_t)r * 64 + g * 8];
        }
        {
            int r = wc * 64 + lm;
            int g = (ks * 2 + hi) ^ (r & 7);
            bq0[ks] = *(const bf16x8*)&cB[(size_t)r * 64 + g * 8];
        }
    }
    if (s1) stage_half256(BT + (size_t)(n0 + 128) * ldb, ldb, oB + 128 * 64, kt1, tid);
    __builtin_amdgcn_s_barrier();
    __builtin_amdgcn_s_setprio(1);
#pragma unroll
    for (int ks = 0; ks < 4; ++ks)
#pragma unroll
        for (int i = 0; i < 2; ++i)
            acc[0][0][i] = __builtin_amdgcn_mfma_f32_32x32x16_bf16(af[ks][i], bq0[ks], acc[0][0][i], 0, 0, 0);
    __builtin_amdgcn_s_setprio(0);
    __builtin_amdgcn_s_barrier();

    // ---- P2: read B(qn1); stage A0(t+2) -> cur A ----
#pragma unroll
    for (int ks = 0; ks < 4; ++ks) {
        int r = wc * 64 + 32 + lm;
        int g = (ks * 2 + hi) ^ (r & 7);
        bq1[ks] = *(const bf16x8*)&cB[(size_t)r * 64 + g * 8];
    }
    if (s2) stage_half256(A + (size_t)m0 * lda, lda, cA, kt2, tid);
    __builtin_amdgcn_s_barrier();
    __builtin_amdgcn_s_setprio(1);
#pragma unroll
    for (int ks = 0; ks < 4; ++ks)
#pragma unroll
        for (int i = 0; i < 2; ++i)
            acc[0][1][i] = __builtin_amdgcn_mfma_f32_32x32x16_bf16(af[ks][i], bq1[ks], acc[0][1][i], 0, 0, 0);
    __builtin_amdgcn_s_setprio(0);
    __builtin_amdgcn_s_barrier();

    // ---- P3: read A(qm1); stage B0(t+2) -> cur B ----
#pragma unroll
    for (int ks = 0; ks < 4; ++ks)
#pragma unroll
        for (int i = 0; i < 2; ++i) {
            int r = wr * 128 + 64 + i * 32 + lm;
            int g = (ks * 2 + hi) ^ (r & 7);
            af[ks][i] = *(const bf16x8*)&cA[(size_t)r * 64 + g * 8];
        }
    if (s2) stage_half256(BT + (size_t)n0 * ldb, ldb, cB, kt2, tid);
    __builtin_amdgcn_s_barrier();
    __builtin_amdgcn_s_setprio(1);
#pragma unroll
    for (int ks = 0; ks < 4; ++ks)
#pragma unroll
        for (int i = 0; i < 2; ++i)
            acc[1][0][i] = __builtin_amdgcn_mfma_f32_32x32x16_bf16(af[ks][i], bq0[ks], acc[1][0][i], 0, 0, 0);
    __builtin_amdgcn_s_setprio(0);
    __builtin_amdgcn_s_barrier();

    // ---- P4: MFMA q11; stage A1(t+2) -> cur A; boundary ----
    __builtin_amdgcn_s_setprio(1);
#pragma unroll
    for (int ks = 0; ks < 4; ++ks)
#pragma unroll
        for (int i = 0; i < 2; ++i)
            acc[1][1][i] = __builtin_amdgcn_mfma_f32_32x32x16_bf16(af[ks][i], bq1[ks], acc[1][1][i], 0, 0, 0);
    __builtin_amdgcn_s_setprio(0);

    if (s2) stage_half256(A + (size_t)(m0 + 128) * lda, lda, cA + 128 * 64, kt2, tid);
    if (s1) {
        if (s2) asm volatile("s_waitcnt vmcnt(6)" ::: "memory");
        else    asm volatile("s_waitcnt vmcnt(0)" ::: "memory");
        __builtin_amdgcn_s_barrier();
    }
}

__global__ __launch_bounds__(512, 2)
void gemm256_kernel(const u16* __restrict__ A, const u16* __restrict__ BT,
                    u16* __restrict__ C, int K, int lda, int ldb, int ldc) {
    __shared__ u16 lds[2][2][256 * 64];   // [buf][A=0/B=1] : 128 KiB

    int gx = gridDim.x;
    int nwg = gx * gridDim.y;
    int orig = blockIdx.y * gx + blockIdx.x;
    int swz = (orig & 7) * (nwg >> 3) + (orig >> 3);
    int by = swz / gx, bx = swz - by * gx;

    const int m0 = by * 256, n0 = bx * 256;
    const int tid = threadIdx.x;
    const int l = tid & 63;
    const int wr = (tid >> 6) >> 2, wc = (tid >> 6) & 3;
    const int NT = K >> 6;                 // must be even

    f32x16 acc[2][2][2] = {};              // [qm][qn][i], 128 f32/lane

    // prologue: tile 0 (4 halves) -> buf0; tile 1 halves {A0,A1,B0} -> buf1
    {
#pragma unroll
        for (int h = 0; h < 2; ++h)
            stage_half256(A + (size_t)(m0 + h * 128) * lda, lda, &lds[0][0][h * 128 * 64], 0, tid);
#pragma unroll
        for (int h = 0; h < 2; ++h)
            stage_half256(BT + (size_t)(n0 + h * 128) * ldb, ldb, &lds[0][1][h * 128 * 64], 0, tid);
        if (NT > 1) {
            stage_half256(A + (size_t)m0 * lda, lda, &lds[1][0][0], 64, tid);
            stage_half256(A + (size_t)(m0 + 128) * lda, lda, &lds[1][0][128 * 64], 64, tid);
            stage_half256(BT + (size_t)n0 * ldb, ldb, &lds[1][1][0], 64, tid);
            asm volatile("s_waitcnt vmcnt(6)" ::: "memory");
        } else {
            asm volatile("s_waitcnt vmcnt(0)" ::: "memory");
        }
        __builtin_amdgcn_s_barrier();
    }

    for (int t = 0; t < NT; t += 2) {
        tile_body256(&lds[0][0][0], &lds[0][1][0], &lds[1][1][0], A, BT, lda, ldb,
                     m0, n0, (t + 1) << 6, (t + 2) << 6, t + 1 < NT, t + 2 < NT, tid, acc);
        tile_body256(&lds[1][0][0], &lds[1][1][0], &lds[0][1][0], A, BT, lda, ldb,
                     m0, n0, (t + 2) << 6, (t + 3) << 6, t + 2 < NT, t + 3 < NT, tid, acc);
    }

    // C/D: col = lane&31, row = (reg&3) + 8*(reg>>2) + 4*(lane>>5)
    const int lc = l & 31, lhi = l >> 5;
#pragma unroll
    for (int qm = 0; qm < 2; ++qm)
#pragma unroll
        for (int i = 0; i < 2; ++i) {
            int rbase = m0 + wr * 128 + qm * 64 + i * 32 + lhi * 4;
#pragma unroll
            for (int qn = 0; qn < 2; ++qn) {
                int col = n0 + wc * 64 + qn * 32 + lc;
#pragma unroll
                for (int reg = 0; reg < 16; ++reg) {
                    int row = rbase + (reg & 3) + ((reg >> 2) << 3);
                    C[(size_t)row * ldc + col] = f2bf(acc[qm][qn][i][reg]);
                }
            }
        }
}

// ---------------------------------------------------------------------------
__global__ __launch_bounds__(256, 2)
void conv_kernel(const float* __restrict__ x, const u16* __restrict__ Y,
                 const u16* __restrict__ Wbf, const float* __restrict__ bias,
                 float* __restrict__ yout, int b0, int Gb, int nPerBlk, int ldy) {
    __shared__ u16 lh[192 * 72];
    const int colsPerN = Gb * 12;
    const int n0 = blockIdx.x * nPerBlk;
    const int tid = threadIdx.x;
    const int w = tid >> 6, l = tid & 63;
    f32x4 acc[4][3] = {};

    for (int k = 0; k < 5; ++k) {
        __syncthreads();
        if (k == 0) {
            const int tot = nPerBlk * Gb * 64;
            for (int it = tid; it < tot; it += 256) {
                int c = it & 63;
                int bn = it >> 6;
                int bl = bn % Gb;
                int nl = bn / Gb;
                const float* src = x + ((size_t)((b0 + bl) * 64 + c) * 2048 + (n0 + nl)) * 12;
                float4 v0 = *(const float4*)(src + 0);
                float4 v1 = *(const float4*)(src + 4);
                float4 v2 = *(const float4*)(src + 8);
                float vv[12];
                *(float4*)&vv[0] = v0; *(float4*)&vv[4] = v1; *(float4*)&vv[8] = v2;
                u16* d = &lh[(nl * colsPerN + bl * 12) * 72 + c];
#pragma unroll
                for (int t = 0; t < 12; ++t) d[t * 72] = f2bf(vv[t]);
            }
        } else {
            for (int it = tid; it < 1536; it += 256) {
                int e8 = it << 3;
                int c = e8 & 63;
                int jj = e8 >> 6;
                int nl = jj / colsPerN;
                int rem = jj - nl * colsPerN;
                const u16* src = Y + (size_t)((k - 1) * 2048 + n0 + nl) * ldy + rem * 64 + c;
                *(u16x8*)&lh[jj * 72 + c] = *(const u16x8*)src;
            }
        }
        __syncthreads();
#pragma unroll
        for (int kk = 0; kk < 2; ++kk) {
            bf16x8 wf[4], hf[3];
#pragma unroll
            for (int i = 0; i < 4; ++i)
                wf[i] = *(const bf16x8*)&Wbf[(size_t)(k * 64 + i * 16 + (l & 15)) * 64 + kk * 32 + (l >> 4) * 8];
#pragma unroll
            for (int j = 0; j < 3; ++j)
                hf[j] = *(const bf16x8*)&lh[(w * 48 + j * 16 + (l & 15)) * 72 + kk * 32 + (l >> 4) * 8];
#pragma unroll
            for (int i = 0; i < 4; ++i)
#pragma unroll
                for (int j = 0; j < 3; ++j)
                    acc[i][j] = __builtin_amdgcn_mfma_f32_16x16x32_bf16(wf[i], hf[j], acc[i][j], 0, 0, 0);
        }
    }

    const int lr = (l >> 4) * 4, lc = l & 15;
#pragma unroll
    for (int j = 0; j < 3; ++j) {
        int jj = w * 48 + j * 16 + lc;
        int nl = jj / colsPerN;
        int rem = jj - nl * colsPerN;
        int bl = rem / 12;
        int t = rem - bl * 12;
#pragma unroll
        for (int i = 0; i < 4; ++i) {
#pragma unroll
            for (int q = 0; q < 4; ++q) {
                int o = i * 16 + lr + q;
                yout[((size_t)((b0 + bl) * 64 + o) * 2048 + (n0 + nl)) * 12 + t] = acc[i][j][q] + bias[o];
            }
        }
    }
}

// ---------------------------------------------------------------------------
extern "C" void kernel_launch(void* const* d_in, const int* in_sizes, int n_in,
                              void* d_out, int out_size, void* d_ws, size_t ws_size,
                              hipStream_t stream) {
    (void)in_sizes; (void)n_in; (void)out_size;
    const float* x  = (const float*)d_in[0];
    const float* A1 = (const float*)d_in[1];
    const float* A2 = (const float*)d_in[2];
    const float* W  = (const float*)d_in[3];
    const float* bs = (const float*)d_in[4];
    float* y = (float*)d_out;
    char* ws = (char*)d_ws;

    const size_t CHUNK_OFF = 33619968;
    u16* astack = (u16*)ws;
    u16* wbf = (u16*)(ws + 33554432);
    u16* a1t = (u16*)(ws + CHUNK_OFF);
    u16* a2t = a1t + (size_t)2048 * 2048;

    size_t avail = ws_size > CHUNK_OFF ? ws_size - CHUNK_OFF : 0;
    int Gb = 16;
    while (Gb > 1 && (size_t)Gb * 15728640 > avail) Gb >>= 1;
    u16* xtT = (u16*)(ws + CHUNK_OFF);
    u16* Yb = xtT + (size_t)Gb * 768 * 2048;
    int ldy = Gb * 768;
    int nPerBlk = 16 / Gb;

    cvt_w_kernel<<<80, 256, 0, stream>>>(W, wbf);
    cvt_a_kernel<<<2048, 256, 0, stream>>>(A1, A2, astack, a1t, a2t);

    gemm_bt_kernel<<<dim3(16, 16, 2), 256, 0, stream>>>(
        astack, a1t, astack + (size_t)2048 * 2048,
        astack + (size_t)4096 * 2048, a2t, astack + (size_t)6144 * 2048,
        2048, 2048, 2048, 2048);

    for (int b0 = 0; b0 < 16; b0 += Gb) {
        pack_x_kernel<<<Gb * 512, 256, 0, stream>>>(x, xtT, b0, Gb);
        gemm256_kernel<<<dim3(ldy / 256, 32), 512, 0, stream>>>(
            astack, xtT, Yb, 2048, 2048, 2048, ldy);
        conv_kernel<<<128 * Gb, 256, 0, stream>>>(x, Yb, wbf, bs, y, b0, Gb, nPerBlk, ldy);
    }
}

// Round 6
// 594.322 us; speedup vs baseline: 1.1077x; 1.1077x over previous
//
#include <hip/hip_runtime.h>

// SparseGraphConv: y = W @ concat([x, A1x, A1^2 x, A2 x, A2^2 x]) + b
// B=16, C=64, N=2048, T=12, C_OUT=64.
//
//   1. cvt_a:   A1,A2 f32 -> bf16 rows of Astack[8192,2048] (+ transposed copies)
//   2. gemm128(z=2): A1^2, A2^2 -> remaining Astack rows
//   3. pack_x:  x[b,c,n,t] f32 -> XtT[(bl*12+t)*64+c][n] bf16 (GEMM B operand)
//                              -> X0[n][(bl*12+t)*64+c] bf16 (hop-0 plane, Y layout)
//   4. gemm256: Y[8192, 12288] = Astack @ XtT^T  (R4-verified schedule, 16x16x32)
//   5. conv:    uniform 5-hop bf16 read from [X0 ; Y]: y = bias + sum_k Wk @ h_k

typedef __attribute__((ext_vector_type(8))) __bf16 bf16x8;
typedef __attribute__((ext_vector_type(4))) float f32x4;
typedef __attribute__((ext_vector_type(8))) unsigned short u16x8;
typedef unsigned short u16;
typedef unsigned int u32;

__device__ __forceinline__ u16 f2bf(float f) {
    u32 u = __float_as_uint(f);
    u32 r = u + 0x7FFFu + ((u >> 16) & 1u);   // round-to-nearest-even
    return (u16)(r >> 16);
}

__device__ __forceinline__ void gload16(const void* g, void* l) {
    __builtin_amdgcn_global_load_lds((const __attribute__((address_space(1))) void*)g,
                                     (__attribute__((address_space(3))) void*)l, 16, 0, 0);
}

// ---------------------------------------------------------------------------
__global__ __launch_bounds__(256)
void cvt_w_kernel(const float* __restrict__ W, u16* __restrict__ wbf) {
    int i = blockIdx.x * 256 + threadIdx.x;
    if (i < 5 * 64 * 64) {
        int c = i & 63;
        int o = (i >> 6) & 63;
        int k = i >> 12;
        wbf[i] = f2bf(W[o * 320 + k * 64 + c]);
    }
}

// ---------------------------------------------------------------------------
__global__ __launch_bounds__(256)
void cvt_a_kernel(const float* __restrict__ A1, const float* __restrict__ A2,
                  u16* __restrict__ astack, u16* __restrict__ a1t, u16* __restrict__ a2t) {
    __shared__ float lt[64][65];
    int bid = blockIdx.x;
    int mat = bid >> 10;
    int ti = bid & 1023;
    int tr = (ti >> 5) << 6;
    int tc = (ti & 31) << 6;
    const float* src = mat ? A2 : A1;
    u16* dstA = astack + (size_t)(mat ? 4096 : 0) * 2048;
    u16* dstT = mat ? a2t : a1t;
    int tid = threadIdx.x;
    int rr = tid >> 4;
    int cc = (tid & 15) << 2;
#pragma unroll
    for (int p = 0; p < 4; ++p) {
        int row = p * 16 + rr;
        float4 v = *(const float4*)&src[(size_t)(tr + row) * 2048 + tc + cc];
        ushort4 o;
        o.x = f2bf(v.x); o.y = f2bf(v.y); o.z = f2bf(v.z); o.w = f2bf(v.w);
        *(ushort4*)&dstA[(size_t)(tr + row) * 2048 + tc + cc] = o;
        lt[row][cc + 0] = v.x; lt[row][cc + 1] = v.y;
        lt[row][cc + 2] = v.z; lt[row][cc + 3] = v.w;
    }
    __syncthreads();
#pragma unroll
    for (int p = 0; p < 4; ++p) {
        int row = p * 16 + rr;
        ushort4 o;
        o.x = f2bf(lt[cc + 0][row]); o.y = f2bf(lt[cc + 1][row]);
        o.z = f2bf(lt[cc + 2][row]); o.w = f2bf(lt[cc + 3][row]);
        *(ushort4*)&dstT[(size_t)(tc + row) * 2048 + tr + cc] = o;
    }
}

// ---------------------------------------------------------------------------
// pack_x: block = 32 nodes x one local batch bl. Emits BOTH layouts via an
// LDS [32][768(+8)] bf16 tile:
//   XtT[bl*768 + (t*64+c)][n]   (GEMM B^T operand, K=n contiguous)
//   X0 [n][bl*768 + t*64 + c]   (hop-0 plane in the Y layout for conv)
__global__ __launch_bounds__(256)
void pack_x_kernel(const float* __restrict__ x, u16* __restrict__ XtT,
                   u16* __restrict__ X0, int b0, int ldy) {
    __shared__ u16 lt[32][776];
    const int bl = blockIdx.x >> 6;          // grid.x = Gb*64
    const int n0 = (blockIdx.x & 63) << 5;   // 64 n-blocks of 32
    const int tid = threadIdx.x;
    const int ng = tid & 31, c8 = tid >> 5;  // 32 n x 8 c-groups
#pragma unroll
    for (int it = 0; it < 8; ++it) {
        int c = it * 8 + c8;
        const float* src = x + ((size_t)((b0 + bl) * 64 + c) * 2048 + n0 + ng) * 12;
        float4 v0 = *(const float4*)(src + 0);
        float4 v1 = *(const float4*)(src + 4);
        float4 v2 = *(const float4*)(src + 8);
        float vv[12];
        *(float4*)&vv[0] = v0; *(float4*)&vv[4] = v1; *(float4*)&vv[8] = v2;
#pragma unroll
        for (int t = 0; t < 12; ++t)
            lt[ng][t * 64 + c] = f2bf(vv[t]);
    }
    __syncthreads();
    // X0 write: row n0+r gets cols [bl*768, bl*768+768) -- 16B chunks, contiguous
    for (int i = tid; i < 3072; i += 256) {
        int r = i / 96, ch = i - r * 96;
        *(u16x8*)&X0[(size_t)(n0 + r) * ldy + bl * 768 + ch * 8] =
            *(const u16x8*)&lt[r][ch * 8];
    }
    // XtT write: row bl*768+rr gets cols [n0, n0+32) -- 4 lanes/row => 64B segments
    for (int i = tid; i < 3072; i += 256) {
        int rr = i >> 2, q = i & 3;
        u16x8 v;
#pragma unroll
        for (int j = 0; j < 8; ++j) v[j] = lt[q * 8 + j][rr];
        *(u16x8*)&XtT[(size_t)(bl * 768 + rr) * 2048 + n0 + q * 8] = v;
    }
}

// ---------------------------------------------------------------------------
// 128^2-tile GEMM (kept for the small A^2 GEMMs).
__global__ __launch_bounds__(256, 2)
void gemm_bt_kernel(const u16* __restrict__ A0, const u16* __restrict__ B0, u16* __restrict__ C0,
                    const u16* __restrict__ A1p, const u16* __restrict__ B1p, u16* __restrict__ C1p,
                    int K, int lda, int ldb, int ldc) {
    const u16* A  = blockIdx.z ? A1p : A0;
    const u16* BT = blockIdx.z ? B1p : B0;
    u16* C        = blockIdx.z ? C1p : C0;

    __shared__ u16 lA[128 * 64];
    __shared__ u16 lB[128 * 64];

    int gx = gridDim.x;
    int nwg = gx * gridDim.y;
    int orig = blockIdx.y * gx + blockIdx.x;
    int swz = (orig & 7) * (nwg >> 3) + (orig >> 3);
    int by = swz / gx, bx = swz - by * gx;

    const int m0 = by * 128, n0 = bx * 128;
    const int tid = threadIdx.x;
    const int w = tid >> 6, l = tid & 63;
    const int wr = w >> 1, wc = w & 1;

    f32x4 acc[4][4] = {};

    const int srow = l >> 3;
    const int scol = ((l & 7) ^ srow) * 8;

    for (int kt = 0; kt < K; kt += 64) {
#pragma unroll
        for (int r = 0; r < 4; ++r) {
            int s = w * 4 + r;
            int row = s * 8 + srow;
            gload16(A + (size_t)(m0 + row) * lda + kt + scol, &lA[s * 512]);
        }
#pragma unroll
        for (int r = 0; r < 4; ++r) {
            int s = w * 4 + r;
            int row = s * 8 + srow;
            gload16(BT + (size_t)(n0 + row) * ldb + kt + scol, &lB[s * 512]);
        }
        __syncthreads();
#pragma unroll
        for (int kk = 0; kk < 2; ++kk) {
            bf16x8 af[4], bfr[4];
            const int cg = ((kk * 4 + (l >> 4)) ^ (l & 7)) * 8;
#pragma unroll
            for (int i = 0; i < 4; ++i)
                af[i] = *(const bf16x8*)&lA[(wr * 64 + i * 16 + (l & 15)) * 64 + cg];
#pragma unroll
            for (int j = 0; j < 4; ++j)
                bfr[j] = *(const bf16x8*)&lB[(wc * 64 + j * 16 + (l & 15)) * 64 + cg];
#pragma unroll
            for (int i = 0; i < 4; ++i)
#pragma unroll
                for (int j = 0; j < 4; ++j)
                    acc[i][j] = __builtin_amdgcn_mfma_f32_16x16x32_bf16(af[i], bfr[j], acc[i][j], 0, 0, 0);
        }
        __syncthreads();
    }

    const int lr = (l >> 4) * 4, lc = l & 15;
#pragma unroll
    for (int i = 0; i < 4; ++i) {
        int row = m0 + wr * 64 + i * 16 + lr;
#pragma unroll
        for (int j = 0; j < 4; ++j) {
            int col = n0 + wc * 64 + j * 16 + lc;
            u16* p = C + (size_t)row * ldc + col;
#pragma unroll
            for (int q = 0; q < 4; ++q)
                p[(size_t)q * ldc] = f2bf(acc[i][j][q]);
        }
    }
}

// ---------------------------------------------------------------------------
// 256^2-tile GEMM -- R4-verified schedule (16x16x32, spread stages, vmcnt(6)).
__device__ __forceinline__ void stage_half256(const u16* __restrict__ src, int ld,
                                              u16* lds, int kt, int tid) {
    int w8 = (tid >> 6) << 3;
    int l = tid & 63;
    int r = l >> 3;
#pragma unroll
    for (int iss = 0; iss < 2; ++iss) {
        int R = iss * 64 + w8 + r;
        gload16(src + (size_t)R * ld + kt + (((l & 7) ^ r) << 3),
                lds + (size_t)(iss * 64 + w8) * 64);
    }
}

__global__ __launch_bounds__(512, 2)
void gemm256_kernel(const u16* __restrict__ A, const u16* __restrict__ BT,
                    u16* __restrict__ C, int K, int lda, int ldb, int ldc) {
    __shared__ u16 lds[2][2][256 * 64];   // [buf][A=0/B=1] : 128 KiB

    int gx = gridDim.x;
    int nwg = gx * gridDim.y;
    int orig = blockIdx.y * gx + blockIdx.x;
    int swz = (orig & 7) * (nwg >> 3) + (orig >> 3);
    int by = swz / gx, bx = swz - by * gx;

    const int m0 = by * 256, n0 = bx * 256;
    const int tid = threadIdx.x;
    const int w = tid >> 6, l = tid & 63;
    const int wr = w >> 2, wc = w & 3;      // 2 x 4 wave grid
    const int NT = K >> 6;

    f32x4 acc[2][2][4][2] = {};             // [qm][qn][i][j]

    // prologue: tile 0 (4 halves) -> buf0; tile 1 halves {A0,A1,B0} -> buf1
    {
#pragma unroll
        for (int h = 0; h < 2; ++h)
            stage_half256(A + (size_t)(m0 + h * 128) * lda, lda, &lds[0][0][h * 128 * 64], 0, tid);
#pragma unroll
        for (int h = 0; h < 2; ++h)
            stage_half256(BT + (size_t)(n0 + h * 128) * ldb, ldb, &lds[0][1][h * 128 * 64], 0, tid);
        if (NT > 1) {
            stage_half256(A + (size_t)m0 * lda, lda, &lds[1][0][0], 64, tid);
            stage_half256(A + (size_t)(m0 + 128) * lda, lda, &lds[1][0][128 * 64], 64, tid);
            stage_half256(BT + (size_t)n0 * ldb, ldb, &lds[1][1][0], 64, tid);
            asm volatile("s_waitcnt vmcnt(6)" ::: "memory");
        } else {
            asm volatile("s_waitcnt vmcnt(0)" ::: "memory");
        }
        __builtin_amdgcn_s_barrier();
    }

    bf16x8 af[2][4];
    bf16x8 bq0[2][2];
    bf16x8 bq1[2][2];

    for (int t = 0; t < NT; ++t) {
        const int cur = t & 1;
        u16* lA = lds[cur][0];
        u16* lB = lds[cur][1];
        const bool s1 = (t + 1 < NT);
        const bool s2 = (t + 2 < NT);
        const int kt1 = (t + 1) << 6;
        const int kt2 = (t + 2) << 6;

        // ---- phase 1: reads A(qm0) + B(qn0); stage B1(t+1) -> buf^1 ----
#pragma unroll
        for (int kk = 0; kk < 2; ++kk) {
#pragma unroll
            for (int i = 0; i < 4; ++i) {
                int r = wr * 128 + i * 16 + (l & 15);
                int g = kk * 4 + (l >> 4);
                af[kk][i] = *(const bf16x8*)&lA[(size_t)r * 64 + ((g ^ (r & 7)) << 3)];
            }
#pragma unroll
            for (int j = 0; j < 2; ++j) {
                int r = wc * 64 + j * 16 + (l & 15);
                int g = kk * 4 + (l >> 4);
                bq0[kk][j] = *(const bf16x8*)&lB[(size_t)r * 64 + ((g ^ (r & 7)) << 3)];
            }
        }
        if (s1)
            stage_half256(BT + (size_t)(n0 + 128) * ldb, ldb, &lds[cur ^ 1][1][128 * 64], kt1, tid);
        __builtin_amdgcn_s_barrier();
        __builtin_amdgcn_s_setprio(1);
#pragma unroll
        for (int kk = 0; kk < 2; ++kk)
#pragma unroll
            for (int i = 0; i < 4; ++i)
#pragma unroll
                for (int j = 0; j < 2; ++j)
                    acc[0][0][i][j] = __builtin_amdgcn_mfma_f32_16x16x32_bf16(af[kk][i], bq0[kk][j], acc[0][0][i][j], 0, 0, 0);
        __builtin_amdgcn_s_setprio(0);
        __builtin_amdgcn_s_barrier();

        // ---- phase 2: reads B(qn1); stage A0(t+2) -> buf cur ----
#pragma unroll
        for (int kk = 0; kk < 2; ++kk)
#pragma unroll
            for (int j = 0; j < 2; ++j) {
                int r = wc * 64 + 32 + j * 16 + (l & 15);
                int g = kk * 4 + (l >> 4);
                bq1[kk][j] = *(const bf16x8*)&lB[(size_t)r * 64 + ((g ^ (r & 7)) << 3)];
            }
        if (s2)
            stage_half256(A + (size_t)m0 * lda, lda, lA, kt2, tid);
        __builtin_amdgcn_s_barrier();
        __builtin_amdgcn_s_setprio(1);
#pragma unroll
        for (int kk = 0; kk < 2; ++kk)
#pragma unroll
            for (int i = 0; i < 4; ++i)
#pragma unroll
                for (int j = 0; j < 2; ++j)
                    acc[0][1][i][j] = __builtin_amdgcn_mfma_f32_16x16x32_bf16(af[kk][i], bq1[kk][j], acc[0][1][i][j], 0, 0, 0);
        __builtin_amdgcn_s_setprio(0);
        __builtin_amdgcn_s_barrier();

        // ---- phase 3: reads A(qm1); stage B0(t+2) -> buf cur ----
#pragma unroll
        for (int kk = 0; kk < 2; ++kk)
#pragma unroll
            for (int i = 0; i < 4; ++i) {
                int r = wr * 128 + 64 + i * 16 + (l & 15);
                int g = kk * 4 + (l >> 4);
                af[kk][i] = *(const bf16x8*)&lA[(size_t)r * 64 + ((g ^ (r & 7)) << 3)];
            }
        if (s2)
            stage_half256(BT + (size_t)n0 * ldb, ldb, lB, kt2, tid);
        __builtin_amdgcn_s_barrier();
        __builtin_amdgcn_s_setprio(1);
#pragma unroll
        for (int kk = 0; kk < 2; ++kk)
#pragma unroll
            for (int i = 0; i < 4; ++i)
#pragma unroll
                for (int j = 0; j < 2; ++j)
                    acc[1][0][i][j] = __builtin_amdgcn_mfma_f32_16x16x32_bf16(af[kk][i], bq0[kk][j], acc[1][0][i][j], 0, 0, 0);
        __builtin_amdgcn_s_setprio(0);
        __builtin_amdgcn_s_barrier();

        // ---- phase 4: MFMA q11; stage A1(t+2) -> buf cur; boundary ----
        __builtin_amdgcn_s_setprio(1);
#pragma unroll
        for (int kk = 0; kk < 2; ++kk)
#pragma unroll
            for (int i = 0; i < 4; ++i)
#pragma unroll
                for (int j = 0; j < 2; ++j)
                    acc[1][1][i][j] = __builtin_amdgcn_mfma_f32_16x16x32_bf16(af[kk][i], bq1[kk][j], acc[1][1][i][j], 0, 0, 0);
        __builtin_amdgcn_s_setprio(0);

        if (s2)
            stage_half256(A + (size_t)(m0 + 128) * lda, lda, lA + 128 * 64, kt2, tid);
        if (s1) {
            if (s2) asm volatile("s_waitcnt vmcnt(6)" ::: "memory");
            else    asm volatile("s_waitcnt vmcnt(0)" ::: "memory");
            __builtin_amdgcn_s_barrier();
        }
    }

    // C/D layout: col = lane&15, row = (lane>>4)*4 + reg
    const int lr = (l >> 4) * 4, lc = l & 15;
#pragma unroll
    for (int qm = 0; qm < 2; ++qm)
#pragma unroll
        for (int i = 0; i < 4; ++i) {
            int row = m0 + wr * 128 + qm * 64 + i * 16 + lr;
#pragma unroll
            for (int qn = 0; qn < 2; ++qn)
#pragma unroll
                for (int j = 0; j < 2; ++j) {
                    int col = n0 + wc * 64 + qn * 32 + j * 16 + lc;
                    u16* p = C + (size_t)row * ldc + col;
#pragma unroll
                    for (int q = 0; q < 4; ++q)
                        p[(size_t)q * ldc] = f2bf(acc[qm][qn][i][j][q]);
                }
        }
}

// ---------------------------------------------------------------------------
// conv: uniform 5-hop bf16 loop. Y5 = [X0 (rows 0..2047) ; Y (rows 2048..10239)],
// hop k at rows k*2048 + n. All staging loads are coalesced u16x8.
__global__ __launch_bounds__(256, 2)
void conv_kernel(const u16* __restrict__ Y5, const u16* __restrict__ Wbf,
                 const float* __restrict__ bias, float* __restrict__ yout,
                 int b0, int Gb, int nPerBlk, int ldy) {
    __shared__ u16 lh[192 * 72];
    const int colsPerN = Gb * 12;
    const int n0 = blockIdx.x * nPerBlk;
    const int tid = threadIdx.x;
    const int w = tid >> 6, l = tid & 63;
    f32x4 acc[4][3] = {};

    for (int k = 0; k < 5; ++k) {
        __syncthreads();
        for (int it = tid; it < 1536; it += 256) {
            int e8 = it << 3;
            int c = e8 & 63;
            int jj = e8 >> 6;
            int nl = jj / colsPerN;
            int rem = jj - nl * colsPerN;
            const u16* src = Y5 + (size_t)(k * 2048 + n0 + nl) * ldy + rem * 64 + c;
            *(u16x8*)&lh[jj * 72 + c] = *(const u16x8*)src;
        }
        __syncthreads();
#pragma unroll
        for (int kk = 0; kk < 2; ++kk) {
            bf16x8 wf[4], hf[3];
#pragma unroll
            for (int i = 0; i < 4; ++i)
                wf[i] = *(const bf16x8*)&Wbf[(size_t)(k * 64 + i * 16 + (l & 15)) * 64 + kk * 32 + (l >> 4) * 8];
#pragma unroll
            for (int j = 0; j < 3; ++j)
                hf[j] = *(const bf16x8*)&lh[(w * 48 + j * 16 + (l & 15)) * 72 + kk * 32 + (l >> 4) * 8];
#pragma unroll
            for (int i = 0; i < 4; ++i)
#pragma unroll
                for (int j = 0; j < 3; ++j)
                    acc[i][j] = __builtin_amdgcn_mfma_f32_16x16x32_bf16(wf[i], hf[j], acc[i][j], 0, 0, 0);
        }
    }

    const int lr = (l >> 4) * 4, lc = l & 15;
#pragma unroll
    for (int j = 0; j < 3; ++j) {
        int jj = w * 48 + j * 16 + lc;
        int nl = jj / colsPerN;
        int rem = jj - nl * colsPerN;
        int bl = rem / 12;
        int t = rem - bl * 12;
#pragma unroll
        for (int i = 0; i < 4; ++i) {
#pragma unroll
            for (int q = 0; q < 4; ++q) {
                int o = i * 16 + lr + q;
                yout[((size_t)((b0 + bl) * 64 + o) * 2048 + (n0 + nl)) * 12 + t] = acc[i][j][q] + bias[o];
            }
        }
    }
}

// ---------------------------------------------------------------------------
extern "C" void kernel_launch(void* const* d_in, const int* in_sizes, int n_in,
                              void* d_out, int out_size, void* d_ws, size_t ws_size,
                              hipStream_t stream) {
    (void)in_sizes; (void)n_in; (void)out_size;
    const float* x  = (const float*)d_in[0];
    const float* A1 = (const float*)d_in[1];
    const float* A2 = (const float*)d_in[2];
    const float* W  = (const float*)d_in[3];
    const float* bs = (const float*)d_in[4];
    float* y = (float*)d_out;
    char* ws = (char*)d_ws;

    // workspace:
    //   [0, 33.5MB)   Astack bf16 [8192][2048]
    //   [33.5MB, ..)  Wbf
    //   [CHUNK_OFF)   transient a1t/a2t, then per-chunk: XtT | X0 | Y
    const size_t CHUNK_OFF = 33619968;
    u16* astack = (u16*)ws;
    u16* wbf = (u16*)(ws + 33554432);
    u16* a1t = (u16*)(ws + CHUNK_OFF);
    u16* a2t = a1t + (size_t)2048 * 2048;

    // per-chunk bytes: XtT Gb*3145728 + X0 Gb*3145728 + Y Gb*12582912
    size_t avail = ws_size > CHUNK_OFF ? ws_size - CHUNK_OFF : 0;
    int Gb = 16;
    while (Gb > 1 && (size_t)Gb * 18874368 > avail) Gb >>= 1;
    int ldy = Gb * 768;
    u16* xtT = (u16*)(ws + CHUNK_OFF);
    u16* x0  = xtT + (size_t)Gb * 768 * 2048;
    u16* Yc  = x0 + (size_t)2048 * ldy;     // GEMM C = hops 1..4
    int nPerBlk = 16 / Gb;

    cvt_w_kernel<<<80, 256, 0, stream>>>(W, wbf);
    cvt_a_kernel<<<2048, 256, 0, stream>>>(A1, A2, astack, a1t, a2t);

    gemm_bt_kernel<<<dim3(16, 16, 2), 256, 0, stream>>>(
        astack, a1t, astack + (size_t)2048 * 2048,
        astack + (size_t)4096 * 2048, a2t, astack + (size_t)6144 * 2048,
        2048, 2048, 2048, 2048);

    for (int b0 = 0; b0 < 16; b0 += Gb) {
        pack_x_kernel<<<Gb * 64, 256, 0, stream>>>(x, xtT, x0, b0, ldy);
        gemm256_kernel<<<dim3(ldy / 256, 32), 512, 0, stream>>>(
            astack, xtT, Yc, 2048, 2048, 2048, ldy);
        conv_kernel<<<128 * Gb, 256, 0, stream>>>(x0, wbf, bs, y, b0, Gb, nPerBlk, ldy);
    }
}

// Round 7
// 491.839 us; speedup vs baseline: 1.3385x; 1.2084x over previous
//
#include <hip/hip_runtime.h>
#include <hip/hip_fp8.h>

// SparseGraphConv: y = W @ concat([x, A1x, A1^2 x, A2 x, A2^2 x]) + b
// B=16, C=64, N=2048, T=12, C_OUT=64.
//
//   1. cvt_a:   A1,A2 f32 -> fp8(x512) rows of Astack8 + bf16 rows + bf16 transposed
//   2. gemm128(z=2): A1^2, A2^2 (bf16 math) -> fp8(x512) rows of Astack8
//   3. pack_x:  x -> XtT8[(bl*12+t)*64+c][n] fp8 (GEMM B op) + X0[n][btc] bf16 (hop-0)
//   4. gemm256: Y[8192, 12288] = (Astack8 @ XtT8^T)/512 -- R4/R6-verified schedule,
//               MX-fp8 mfma_scale_f32_16x16x128_f8f6f4 (scales = 1.0)
//   5. conv:    uniform 5-hop bf16 read from [X0 ; Y]

typedef __attribute__((ext_vector_type(8))) __bf16 bf16x8;
typedef __attribute__((ext_vector_type(4))) float f32x4;
typedef __attribute__((ext_vector_type(4))) int i32x4;
typedef __attribute__((ext_vector_type(8))) int i32x8;
typedef __attribute__((ext_vector_type(8))) unsigned short u16x8;
typedef unsigned short u16;
typedef unsigned int u32;
typedef unsigned char u8;

__device__ __forceinline__ u16 f2bf(float f) {
    u32 u = __float_as_uint(f);
    u32 r = u + 0x7FFFu + ((u >> 16) & 1u);   // round-to-nearest-even
    return (u16)(r >> 16);
}

__device__ __forceinline__ u8 f2fp8(float f) {
    __hip_fp8_e4m3 v(f);
    return *(u8*)&v;
}

__device__ __forceinline__ float bf2f(u16 v) {
    return __uint_as_float((u32)v << 16);
}

__device__ __forceinline__ void gload16(const void* g, void* l) {
    __builtin_amdgcn_global_load_lds((const __attribute__((address_space(1))) void*)g,
                                     (__attribute__((address_space(3))) void*)l, 16, 0, 0);
}

// ---------------------------------------------------------------------------
__global__ __launch_bounds__(256)
void cvt_w_kernel(const float* __restrict__ W, u16* __restrict__ wbf) {
    int i = blockIdx.x * 256 + threadIdx.x;
    if (i < 5 * 64 * 64) {
        int c = i & 63;
        int o = (i >> 6) & 63;
        int k = i >> 12;
        wbf[i] = f2bf(W[o * 320 + k * 64 + c]);
    }
}

// ---------------------------------------------------------------------------
// A1,A2 f32 -> fp8(x512) direct rows of Astack8 (0..2047 / 4096..6143)
//           -> bf16 rows (a1b/a2b, gemm128 A-operand)
//           -> bf16 transposed (a1t/a2t, gemm128 BT-operand)
__global__ __launch_bounds__(256)
void cvt_a_kernel(const float* __restrict__ A1, const float* __restrict__ A2,
                  u8* __restrict__ astack8, u16* __restrict__ a1b, u16* __restrict__ a2b,
                  u16* __restrict__ a1t, u16* __restrict__ a2t) {
    __shared__ float lt[64][65];
    int bid = blockIdx.x;
    int mat = bid >> 10;
    int ti = bid & 1023;
    int tr = (ti >> 5) << 6;
    int tc = (ti & 31) << 6;
    const float* src = mat ? A2 : A1;
    u8* dst8 = astack8 + (size_t)(mat ? 4096 : 0) * 2048;
    u16* dstB = mat ? a2b : a1b;
    u16* dstT = mat ? a2t : a1t;
    int tid = threadIdx.x;
    int rr = tid >> 4;
    int cc = (tid & 15) << 2;
#pragma unroll
    for (int p = 0; p < 4; ++p) {
        int row = p * 16 + rr;
        float4 v = *(const float4*)&src[(size_t)(tr + row) * 2048 + tc + cc];
        ushort4 o;
        o.x = f2bf(v.x); o.y = f2bf(v.y); o.z = f2bf(v.z); o.w = f2bf(v.w);
        *(ushort4*)&dstB[(size_t)(tr + row) * 2048 + tc + cc] = o;
        u32 w = (u32)f2fp8(v.x * 512.f) | ((u32)f2fp8(v.y * 512.f) << 8) |
                ((u32)f2fp8(v.z * 512.f) << 16) | ((u32)f2fp8(v.w * 512.f) << 24);
        *(u32*)&dst8[(size_t)(tr + row) * 2048 + tc + cc] = w;
        lt[row][cc + 0] = v.x; lt[row][cc + 1] = v.y;
        lt[row][cc + 2] = v.z; lt[row][cc + 3] = v.w;
    }
    __syncthreads();
#pragma unroll
    for (int p = 0; p < 4; ++p) {
        int row = p * 16 + rr;
        ushort4 o;
        o.x = f2bf(lt[cc + 0][row]); o.y = f2bf(lt[cc + 1][row]);
        o.z = f2bf(lt[cc + 2][row]); o.w = f2bf(lt[cc + 3][row]);
        *(ushort4*)&dstT[(size_t)(tc + row) * 2048 + tr + cc] = o;
    }
}

// ---------------------------------------------------------------------------
// pack_x: block = 32 nodes x one local batch bl; LDS [32][768(+8)] bf16 tile.
//   XtT8[bl*768 + (t*64+c)][n]  fp8  (GEMM B^T operand)
//   X0 [n][bl*768 + t*64 + c]   bf16 (hop-0 plane in Y layout)
__global__ __launch_bounds__(256)
void pack_x_kernel(const float* __restrict__ x, u8* __restrict__ XtT8,
                   u16* __restrict__ X0, int b0, int ldy) {
    __shared__ u16 lt[32][776];
    const int bl = blockIdx.x >> 6;
    const int n0 = (blockIdx.x & 63) << 5;
    const int tid = threadIdx.x;
    const int ng = tid & 31, c8 = tid >> 5;
#pragma unroll
    for (int it = 0; it < 8; ++it) {
        int c = it * 8 + c8;
        const float* src = x + ((size_t)((b0 + bl) * 64 + c) * 2048 + n0 + ng) * 12;
        float4 v0 = *(const float4*)(src + 0);
        float4 v1 = *(const float4*)(src + 4);
        float4 v2 = *(const float4*)(src + 8);
        float vv[12];
        *(float4*)&vv[0] = v0; *(float4*)&vv[4] = v1; *(float4*)&vv[8] = v2;
#pragma unroll
        for (int t = 0; t < 12; ++t)
            lt[ng][t * 64 + c] = f2bf(vv[t]);
    }
    __syncthreads();
    for (int i = tid; i < 3072; i += 256) {
        int r = i / 96, ch = i - r * 96;
        *(u16x8*)&X0[(size_t)(n0 + r) * ldy + bl * 768 + ch * 8] =
            *(const u16x8*)&lt[r][ch * 8];
    }
    for (int i = tid; i < 3072; i += 256) {
        int rr = i >> 2, q = i & 3;
        u8 b[8];
#pragma unroll
        for (int j = 0; j < 8; ++j) b[j] = f2fp8(bf2f(lt[q * 8 + j][rr]));
        uint2 w;
        w.x = (u32)b[0] | ((u32)b[1] << 8) | ((u32)b[2] << 16) | ((u32)b[3] << 24);
        w.y = (u32)b[4] | ((u32)b[5] << 8) | ((u32)b[6] << 16) | ((u32)b[7] << 24);
        *(uint2*)&XtT8[(size_t)(bl * 768 + rr) * 2048 + n0 + q * 8] = w;
    }
}

// ---------------------------------------------------------------------------
// 128^2-tile bf16 GEMM for A^2; epilogue writes fp8 scaled x512.
__global__ __launch_bounds__(256, 2)
void gemm_bt_kernel(const u16* __restrict__ A0, const u16* __restrict__ B0, u8* __restrict__ C0,
                    const u16* __restrict__ A1p, const u16* __restrict__ B1p, u8* __restrict__ C1p,
                    int K, int lda, int ldb, int ldc) {
    const u16* A  = blockIdx.z ? A1p : A0;
    const u16* BT = blockIdx.z ? B1p : B0;
    u8* C         = blockIdx.z ? C1p : C0;

    __shared__ u16 lA[128 * 64];
    __shared__ u16 lB[128 * 64];

    int gx = gridDim.x;
    int nwg = gx * gridDim.y;
    int orig = blockIdx.y * gx + blockIdx.x;
    int swz = (orig & 7) * (nwg >> 3) + (orig >> 3);
    int by = swz / gx, bx = swz - by * gx;

    const int m0 = by * 128, n0 = bx * 128;
    const int tid = threadIdx.x;
    const int w = tid >> 6, l = tid & 63;
    const int wr = w >> 1, wc = w & 1;

    f32x4 acc[4][4] = {};

    const int srow = l >> 3;
    const int scol = ((l & 7) ^ srow) * 8;

    for (int kt = 0; kt < K; kt += 64) {
#pragma unroll
        for (int r = 0; r < 4; ++r) {
            int s = w * 4 + r;
            int row = s * 8 + srow;
            gload16(A + (size_t)(m0 + row) * lda + kt + scol, &lA[s * 512]);
        }
#pragma unroll
        for (int r = 0; r < 4; ++r) {
            int s = w * 4 + r;
            int row = s * 8 + srow;
            gload16(BT + (size_t)(n0 + row) * ldb + kt + scol, &lB[s * 512]);
        }
        __syncthreads();
#pragma unroll
        for (int kk = 0; kk < 2; ++kk) {
            bf16x8 af[4], bfr[4];
            const int cg = ((kk * 4 + (l >> 4)) ^ (l & 7)) * 8;
#pragma unroll
            for (int i = 0; i < 4; ++i)
                af[i] = *(const bf16x8*)&lA[(wr * 64 + i * 16 + (l & 15)) * 64 + cg];
#pragma unroll
            for (int j = 0; j < 4; ++j)
                bfr[j] = *(const bf16x8*)&lB[(wc * 64 + j * 16 + (l & 15)) * 64 + cg];
#pragma unroll
            for (int i = 0; i < 4; ++i)
#pragma unroll
                for (int j = 0; j < 4; ++j)
                    acc[i][j] = __builtin_amdgcn_mfma_f32_16x16x32_bf16(af[i], bfr[j], acc[i][j], 0, 0, 0);
        }
        __syncthreads();
    }

    const int lr = (l >> 4) * 4, lc = l & 15;
#pragma unroll
    for (int i = 0; i < 4; ++i) {
        int row = m0 + wr * 64 + i * 16 + lr;
#pragma unroll
        for (int j = 0; j < 4; ++j) {
            int col = n0 + wc * 64 + j * 16 + lc;
            u8* p = C + (size_t)row * ldc + col;
#pragma unroll
            for (int q = 0; q < 4; ++q)
                p[(size_t)q * ldc] = f2fp8(acc[i][j][q] * 512.f);
        }
    }
}

// ---------------------------------------------------------------------------
// 256^2-tile MX-fp8 GEMM. Byte-geometry identical to the verified bf16 R4/R6
// kernel (rows = 128 B, half-tile 16 KB, same stage/vmcnt/barrier skeleton);
// math = mfma_scale_f32_16x16x128_f8f6f4, fmt fp8/fp8, scales pinned to 1.0.
// Per tile: K=128 (NT=16). Frags: A row r = base+i*16+(l&15), k-bytes
// (l>>4)*32 + [0,32) -> two swizzled b128 reads.
__device__ __forceinline__ void stage_half256(const u8* __restrict__ src, int ld,
                                              u8* lds, int kt, int tid) {
    int w8 = (tid >> 6) << 3;
    int l = tid & 63;
    int r = l >> 3;
#pragma unroll
    for (int iss = 0; iss < 2; ++iss) {
        int R = iss * 64 + w8 + r;
        gload16(src + (size_t)R * ld + kt + (((l & 7) ^ r) << 4),
                lds + (size_t)(iss * 64 + w8) * 128);
    }
}

__device__ __forceinline__ i32x8 ldfrag(const u8* lds, int r, int g0) {
    const int s = r & 7;
    i32x4 lo = *(const i32x4*)&lds[(size_t)r * 128 + ((g0 ^ s) << 4)];
    i32x4 hi = *(const i32x4*)&lds[(size_t)r * 128 + (((g0 + 1) ^ s) << 4)];
    i32x8 v = {lo[0], lo[1], lo[2], lo[3], hi[0], hi[1], hi[2], hi[3]};
    return v;
}

#define MFMA8(ACC, AF, BF)                                                              \
    _Pragma("unroll")                                                                    \
    for (int i = 0; i < 4; ++i)                                                          \
        _Pragma("unroll")                                                                \
        for (int j = 0; j < 2; ++j)                                                      \
            ACC[i][j] = __builtin_amdgcn_mfma_scale_f32_16x16x128_f8f6f4(                \
                AF[i], BF[j], ACC[i][j], 0, 0, 0, 0x7F7F7F7F, 0, 0x7F7F7F7F);

__global__ __launch_bounds__(512, 2)
void gemm256_kernel(const u8* __restrict__ A, const u8* __restrict__ BT,
                    u16* __restrict__ C, int K, int lda, int ldb, int ldc) {
    __shared__ u8 lds8[2][2][256 * 128];   // [buf][A=0/B=1] : 128 KiB

    int gx = gridDim.x;
    int nwg = gx * gridDim.y;
    int orig = blockIdx.y * gx + blockIdx.x;
    int swz = (orig & 7) * (nwg >> 3) + (orig >> 3);
    int by = swz / gx, bx = swz - by * gx;

    const int m0 = by * 256, n0 = bx * 256;
    const int tid = threadIdx.x;
    const int w = tid >> 6, l = tid & 63;
    const int wr = w >> 2, wc = w & 3;      // 2 x 4 wave grid
    const int NT = K >> 7;                  // K in bytes, 128/tile

    f32x4 acc[2][2][4][2] = {};             // [qm][qn][i][j]

    // prologue: tile 0 (4 halves) -> buf0; tile 1 {A0,A1,B0} -> buf1
    {
        stage_half256(A + (size_t)m0 * lda, lda, &lds8[0][0][0], 0, tid);
        stage_half256(A + (size_t)(m0 + 128) * lda, lda, &lds8[0][0][128 * 128], 0, tid);
        stage_half256(BT + (size_t)n0 * ldb, ldb, &lds8[0][1][0], 0, tid);
        stage_half256(BT + (size_t)(n0 + 128) * ldb, ldb, &lds8[0][1][128 * 128], 0, tid);
        if (NT > 1) {
            stage_half256(A + (size_t)m0 * lda, lda, &lds8[1][0][0], 128, tid);
            stage_half256(A + (size_t)(m0 + 128) * lda, lda, &lds8[1][0][128 * 128], 128, tid);
            stage_half256(BT + (size_t)n0 * ldb, ldb, &lds8[1][1][0], 128, tid);
            asm volatile("s_waitcnt vmcnt(6)" ::: "memory");
        } else {
            asm volatile("s_waitcnt vmcnt(0)" ::: "memory");
        }
        __builtin_amdgcn_s_barrier();
    }

    const int lm = l & 15;
    const int g0 = (l >> 4) * 2;
    i32x8 af[4], b0[2], b1[2];

    for (int t = 0; t < NT; ++t) {
        const int cur = t & 1;
        u8* lA = lds8[cur][0];
        u8* lB = lds8[cur][1];
        const bool s1 = (t + 1 < NT);
        const bool s2 = (t + 2 < NT);
        const int kt1 = (t + 1) << 7;
        const int kt2 = (t + 2) << 7;

        // ---- phase 1: reads A(qm0)+B(qn0); stage B1(t+1) -> buf^1 ----
#pragma unroll
        for (int i = 0; i < 4; ++i)
            af[i] = ldfrag(lA, wr * 128 + i * 16 + lm, g0);
#pragma unroll
        for (int j = 0; j < 2; ++j)
            b0[j] = ldfrag(lB, wc * 64 + j * 16 + lm, g0);
        if (s1)
            stage_half256(BT + (size_t)(n0 + 128) * ldb, ldb, &lds8[cur ^ 1][1][128 * 128], kt1, tid);
        __builtin_amdgcn_s_barrier();
        __builtin_amdgcn_s_setprio(1);
        MFMA8(acc[0][0], af, b0);
        __builtin_amdgcn_s_setprio(0);
        __builtin_amdgcn_s_barrier();

        // ---- phase 2: reads B(qn1); stage A0(t+2) -> buf cur ----
#pragma unroll
        for (int j = 0; j < 2; ++j)
            b1[j] = ldfrag(lB, wc * 64 + 32 + j * 16 + lm, g0);
        if (s2)
            stage_half256(A + (size_t)m0 * lda, lda, lA, kt2, tid);
        __builtin_amdgcn_s_barrier();
        __builtin_amdgcn_s_setprio(1);
        MFMA8(acc[0][1], af, b1);
        __builtin_amdgcn_s_setprio(0);
        __builtin_amdgcn_s_barrier();

        // ---- phase 3: reads A(qm1); stage B0(t+2) -> buf cur ----
#pragma unroll
        for (int i = 0; i < 4; ++i)
            af[i] = ldfrag(lA, wr * 128 + 64 + i * 16 + lm, g0);
        if (s2)
            stage_half256(BT + (size_t)n0 * ldb, ldb, lB, kt2, tid);
        __builtin_amdgcn_s_barrier();
        __builtin_amdgcn_s_setprio(1);
        MFMA8(acc[1][0], af, b0);
        __builtin_amdgcn_s_setprio(0);
        __builtin_amdgcn_s_barrier();

        // ---- phase 4: MFMA q11; stage A1(t+2) -> buf cur; boundary ----
        __builtin_amdgcn_s_setprio(1);
        MFMA8(acc[1][1], af, b1);
        __builtin_amdgcn_s_setprio(0);

        if (s2)
            stage_half256(A + (size_t)(m0 + 128) * lda, lda, lA + 128 * 128, kt2, tid);
        if (s1) {
            if (s2) asm volatile("s_waitcnt vmcnt(6)" ::: "memory");
            else    asm volatile("s_waitcnt vmcnt(0)" ::: "memory");
            __builtin_amdgcn_s_barrier();
        }
    }

    // C/D layout (shape-determined): col = lane&15, row = (lane>>4)*4 + reg
    const int lr = (l >> 4) * 4, lc = l & 15;
    const float ds = 1.f / 512.f;
#pragma unroll
    for (int qm = 0; qm < 2; ++qm)
#pragma unroll
        for (int i = 0; i < 4; ++i) {
            int row = m0 + wr * 128 + qm * 64 + i * 16 + lr;
#pragma unroll
            for (int qn = 0; qn < 2; ++qn)
#pragma unroll
                for (int j = 0; j < 2; ++j) {
                    int col = n0 + wc * 64 + qn * 32 + j * 16 + lc;
                    u16* p = C + (size_t)row * ldc + col;
#pragma unroll
                    for (int q = 0; q < 4; ++q)
                        p[(size_t)q * ldc] = f2bf(acc[qm][qn][i][j][q] * ds);
                }
        }
}

// ---------------------------------------------------------------------------
// conv: uniform 5-hop bf16 loop over Y5 = [X0 ; Y].
__global__ __launch_bounds__(256, 2)
void conv_kernel(const u16* __restrict__ Y5, const u16* __restrict__ Wbf,
                 const float* __restrict__ bias, float* __restrict__ yout,
                 int b0, int Gb, int nPerBlk, int ldy) {
    __shared__ u16 lh[192 * 72];
    const int colsPerN = Gb * 12;
    const int n0 = blockIdx.x * nPerBlk;
    const int tid = threadIdx.x;
    const int w = tid >> 6, l = tid & 63;
    f32x4 acc[4][3] = {};

    for (int k = 0; k < 5; ++k) {
        __syncthreads();
        for (int it = tid; it < 1536; it += 256) {
            int e8 = it << 3;
            int c = e8 & 63;
            int jj = e8 >> 6;
            int nl = jj / colsPerN;
            int rem = jj - nl * colsPerN;
            const u16* src = Y5 + (size_t)(k * 2048 + n0 + nl) * ldy + rem * 64 + c;
            *(u16x8*)&lh[jj * 72 + c] = *(const u16x8*)src;
        }
        __syncthreads();
#pragma unroll
        for (int kk = 0; kk < 2; ++kk) {
            bf16x8 wf[4], hf[3];
#pragma unroll
            for (int i = 0; i < 4; ++i)
                wf[i] = *(const bf16x8*)&Wbf[(size_t)(k * 64 + i * 16 + (l & 15)) * 64 + kk * 32 + (l >> 4) * 8];
#pragma unroll
            for (int j = 0; j < 3; ++j)
                hf[j] = *(const bf16x8*)&lh[(w * 48 + j * 16 + (l & 15)) * 72 + kk * 32 + (l >> 4) * 8];
#pragma unroll
            for (int i = 0; i < 4; ++i)
#pragma unroll
                for (int j = 0; j < 3; ++j)
                    acc[i][j] = __builtin_amdgcn_mfma_f32_16x16x32_bf16(wf[i], hf[j], acc[i][j], 0, 0, 0);
        }
    }

    const int lr = (l >> 4) * 4, lc = l & 15;
#pragma unroll
    for (int j = 0; j < 3; ++j) {
        int jj = w * 48 + j * 16 + lc;
        int nl = jj / colsPerN;
        int rem = jj - nl * colsPerN;
        int bl = rem / 12;
        int t = rem - bl * 12;
#pragma unroll
        for (int i = 0; i < 4; ++i) {
#pragma unroll
            for (int q = 0; q < 4; ++q) {
                int o = i * 16 + lr + q;
                yout[((size_t)((b0 + bl) * 64 + o) * 2048 + (n0 + nl)) * 12 + t] = acc[i][j][q] + bias[o];
            }
        }
    }
}

// ---------------------------------------------------------------------------
extern "C" void kernel_launch(void* const* d_in, const int* in_sizes, int n_in,
                              void* d_out, int out_size, void* d_ws, size_t ws_size,
                              hipStream_t stream) {
    (void)in_sizes; (void)n_in; (void)out_size;
    const float* x  = (const float*)d_in[0];
    const float* A1 = (const float*)d_in[1];
    const float* A2 = (const float*)d_in[2];
    const float* W  = (const float*)d_in[3];
    const float* bs = (const float*)d_in[4];
    float* y = (float*)d_out;
    char* ws = (char*)d_ws;

    // workspace:
    //   [0, 16.78M)      Astack8 fp8 [8192][2048] (A*512)
    //   [16.78M, +64K)   Wbf
    //   [CHUNK_OFF)      transient a1b,a2b,a1t,a2t (bf16), then per-chunk XtT8|X0|Y
    const size_t CHUNK_OFF = 16842752;
    u8* astack8 = (u8*)ws;
    u16* wbf = (u16*)(ws + 16777216);
    u16* a1b = (u16*)(ws + CHUNK_OFF);
    u16* a2b = a1b + (size_t)2048 * 2048;
    u16* a1t = a2b + (size_t)2048 * 2048;
    u16* a2t = a1t + (size_t)2048 * 2048;

    // per-chunk bytes: XtT8 Gb*1572864 + X0 Gb*3145728 + Y Gb*12582912
    size_t avail = ws_size > CHUNK_OFF ? ws_size - CHUNK_OFF : 0;
    int Gb = 16;
    while (Gb > 1 && (size_t)Gb * 17301504 > avail) Gb >>= 1;
    int ldy = Gb * 768;
    u8* xtT8 = (u8*)(ws + CHUNK_OFF);
    u16* x0  = (u16*)(xtT8 + (size_t)Gb * 768 * 2048);
    u16* Yc  = x0 + (size_t)2048 * ldy;     // GEMM C = hops 1..4
    int nPerBlk = 16 / Gb;

    cvt_w_kernel<<<80, 256, 0, stream>>>(W, wbf);
    cvt_a_kernel<<<2048, 256, 0, stream>>>(A1, A2, astack8, a1b, a2b, a1t, a2t);

    gemm_bt_kernel<<<dim3(16, 16, 2), 256, 0, stream>>>(
        a1b, a1t, astack8 + (size_t)2048 * 2048,
        a2b, a2t, astack8 + (size_t)6144 * 2048,
        2048, 2048, 2048, 2048);

    for (int b0 = 0; b0 < 16; b0 += Gb) {
        pack_x_kernel<<<Gb * 64, 256, 0, stream>>>(x, xtT8, x0, b0, ldy);
        gemm256_kernel<<<dim3(ldy / 256, 32), 512, 0, stream>>>(
            astack8, xtT8, Yc, 2048, 2048, 2048, ldy);
        conv_kernel<<<128 * Gb, 256, 0, stream>>>(x0, wbf, bs, y, b0, Gb, nPerBlk, ldy);
    }
}

// Round 8
// 411.713 us; speedup vs baseline: 1.5990x; 1.1946x over previous
//
#include <hip/hip_runtime.h>

// SparseGraphConv: y = W @ concat([x, A1x, A1^2 x, A2 x, A2^2 x]) + b
// B=16, C=64, N=2048, T=12, C_OUT=64.
//
//   1. cvt_a:   A1,A2 f32 -> fp4(x8192) rows of Astack4 + bf16 rows + bf16 transposed
//   2. gemm128(z=2): A1^2, A2^2 (bf16 math) -> a2sq bf16 temp
//   3. pack_a2: a2sq bf16 -> fp4(x8192) rows of Astack4
//   4. pack_x:  x -> XtT4[(bl*12+t)*64+c][n] fp4 + X0[n][btc] bf16 (hop-0)
//   5. gemm256: Y = (Astack4 @ XtT4^T)/8192 -- R4/R6/R7-verified skeleton,
//               MX-fp4 mfma_scale_f32_16x16x128_f8f6f4 (cbsz=blgp=4, scales=1.0).
//               K-tile = 256 fp4 elems = 128 B rows -> staging geometry identical
//               to the verified bf16/fp8 kernels; frag reads = single b128 at
//               slot (kk*4+h)^(r&7) = the bf16 pattern that measured 0 conflicts.
//   6. conv:    uniform 5-hop bf16 read from [X0 ; Y]

typedef __attribute__((ext_vector_type(8))) __bf16 bf16x8;
typedef __attribute__((ext_vector_type(4))) float f32x4;
typedef __attribute__((ext_vector_type(4))) int i32x4;
typedef __attribute__((ext_vector_type(8))) int i32x8;
typedef __attribute__((ext_vector_type(8))) unsigned short u16x8;
typedef unsigned short u16;
typedef unsigned int u32;
typedef unsigned char u8;

__device__ __forceinline__ u16 f2bf(float f) {
    u32 u = __float_as_uint(f);
    u32 r = u + 0x7FFFu + ((u >> 16) & 1u);   // round-to-nearest-even
    return (u16)(r >> 16);
}

__device__ __forceinline__ float bf2f(u16 v) {
    return __uint_as_float((u32)v << 16);
}

// e2m1 nibble encode, round-to-nearest; levels {0,.5,1,1.5,2,3,4,6}
__device__ __forceinline__ u32 f2fp4(float f) {
    u32 s = (__float_as_uint(f) >> 31) << 3;
    float m = fabsf(f);
    u32 c;
    if      (m < 0.25f) c = 0;
    else if (m < 0.75f) c = 1;
    else if (m < 1.25f) c = 2;
    else if (m < 1.75f) c = 3;
    else if (m < 2.5f)  c = 4;
    else if (m < 3.5f)  c = 5;
    else if (m < 5.0f)  c = 6;
    else                c = 7;
    return s | c;
}

__device__ __forceinline__ void gload16(const void* g, void* l) {
    __builtin_amdgcn_global_load_lds((const __attribute__((address_space(1))) void*)g,
                                     (__attribute__((address_space(3))) void*)l, 16, 0, 0);
}

#define ASCALE 8192.f
#define DSCALE (1.f / 8192.f)

// ---------------------------------------------------------------------------
__global__ __launch_bounds__(256)
void cvt_w_kernel(const float* __restrict__ W, u16* __restrict__ wbf) {
    int i = blockIdx.x * 256 + threadIdx.x;
    if (i < 5 * 64 * 64) {
        int c = i & 63;
        int o = (i >> 6) & 63;
        int k = i >> 12;
        wbf[i] = f2bf(W[o * 320 + k * 64 + c]);
    }
}

// ---------------------------------------------------------------------------
// A1,A2 f32 -> fp4(x8192) direct rows of Astack4 (0..2047 / 4096..6143)
//           -> bf16 rows (a1b/a2b) + bf16 transposed (a1t/a2t) for gemm128
__global__ __launch_bounds__(256)
void cvt_a_kernel(const float* __restrict__ A1, const float* __restrict__ A2,
                  u8* __restrict__ astack4, u16* __restrict__ a1b, u16* __restrict__ a2b,
                  u16* __restrict__ a1t, u16* __restrict__ a2t) {
    __shared__ float lt[64][65];
    int bid = blockIdx.x;
    int mat = bid >> 10;
    int ti = bid & 1023;
    int tr = (ti >> 5) << 6;
    int tc = (ti & 31) << 6;
    const float* src = mat ? A2 : A1;
    u8* dst4 = astack4 + (size_t)(mat ? 4096 : 0) * 1024;
    u16* dstB = mat ? a2b : a1b;
    u16* dstT = mat ? a2t : a1t;
    int tid = threadIdx.x;
    int rr = tid >> 4;
    int cc = (tid & 15) << 2;
#pragma unroll
    for (int p = 0; p < 4; ++p) {
        int row = p * 16 + rr;
        float4 v = *(const float4*)&src[(size_t)(tr + row) * 2048 + tc + cc];
        ushort4 o;
        o.x = f2bf(v.x); o.y = f2bf(v.y); o.z = f2bf(v.z); o.w = f2bf(v.w);
        *(ushort4*)&dstB[(size_t)(tr + row) * 2048 + tc + cc] = o;
        u16 w4 = (u16)(f2fp4(v.x * ASCALE) | (f2fp4(v.y * ASCALE) << 4) |
                       (f2fp4(v.z * ASCALE) << 8) | (f2fp4(v.w * ASCALE) << 12));
        *(u16*)&dst4[(size_t)(tr + row) * 1024 + ((tc + cc) >> 1)] = w4;
        lt[row][cc + 0] = v.x; lt[row][cc + 1] = v.y;
        lt[row][cc + 2] = v.z; lt[row][cc + 3] = v.w;
    }
    __syncthreads();
#pragma unroll
    for (int p = 0; p < 4; ++p) {
        int row = p * 16 + rr;
        ushort4 o;
        o.x = f2bf(lt[cc + 0][row]); o.y = f2bf(lt[cc + 1][row]);
        o.z = f2bf(lt[cc + 2][row]); o.w = f2bf(lt[cc + 3][row]);
        *(ushort4*)&dstT[(size_t)(tc + row) * 2048 + tr + cc] = o;
    }
}

// ---------------------------------------------------------------------------
// a2sq bf16 [4096][2048] (A1^2 ; A2^2) -> fp4(x8192) Astack4 rows 2048.. / 6144..
__global__ __launch_bounds__(256)
void pack_a2_kernel(const u16* __restrict__ a2sq, u8* __restrict__ astack4) {
    int i = blockIdx.x * 256 + threadIdx.x;   // 4096 blocks: 8 elems/thread
    int e = i << 3;
    int r = e >> 11, c = e & 2047;
    const u16* s = a2sq + ((size_t)r << 11) + c;
    u16x8 v = *(const u16x8*)s;
    u32 w = 0;
#pragma unroll
    for (int j = 0; j < 8; ++j)
        w |= f2fp4(bf2f(v[j]) * ASCALE) << (4 * j);
    int row = (r < 2048) ? (2048 + r) : (4096 + r);
    *(u32*)&astack4[(size_t)row * 1024 + (c >> 1)] = w;
}

// ---------------------------------------------------------------------------
// pack_x: block = 32 nodes x one local batch bl; LDS [32][768(+8)] bf16 tile.
//   XtT4[bl*768 + (t*64+c)][n]  fp4 (GEMM B^T operand, n pairs per byte)
//   X0 [n][bl*768 + t*64 + c]   bf16 (hop-0 plane in Y layout)
__global__ __launch_bounds__(256)
void pack_x_kernel(const float* __restrict__ x, u8* __restrict__ XtT4,
                   u16* __restrict__ X0, int b0, int ldy) {
    __shared__ u16 lt[32][776];
    const int bl = blockIdx.x >> 6;
    const int n0 = (blockIdx.x & 63) << 5;
    const int tid = threadIdx.x;
    const int ng = tid & 31, c8 = tid >> 5;
#pragma unroll
    for (int it = 0; it < 8; ++it) {
        int c = it * 8 + c8;
        const float* src = x + ((size_t)((b0 + bl) * 64 + c) * 2048 + n0 + ng) * 12;
        float4 v0 = *(const float4*)(src + 0);
        float4 v1 = *(const float4*)(src + 4);
        float4 v2 = *(const float4*)(src + 8);
        float vv[12];
        *(float4*)&vv[0] = v0; *(float4*)&vv[4] = v1; *(float4*)&vv[8] = v2;
#pragma unroll
        for (int t = 0; t < 12; ++t)
            lt[ng][t * 64 + c] = f2bf(vv[t]);
    }
    __syncthreads();
    for (int i = tid; i < 3072; i += 256) {
        int r = i / 96, ch = i - r * 96;
        *(u16x8*)&X0[(size_t)(n0 + r) * ldy + bl * 768 + ch * 8] =
            *(const u16x8*)&lt[r][ch * 8];
    }
    // XtT4: thread packs 16 n-values -> 8 bytes
    for (int i = tid; i < 1536; i += 256) {
        int rr = i >> 1, q = i & 1;
        uint2 w;
        u32 lo = 0, hi = 0;
#pragma unroll
        for (int j = 0; j < 4; ++j) {
            lo |= f2fp4(bf2f(lt[q * 16 + 2 * j + 0][rr])) << (8 * j);
            lo |= f2fp4(bf2f(lt[q * 16 + 2 * j + 1][rr])) << (8 * j + 4);
            hi |= f2fp4(bf2f(lt[q * 16 + 8 + 2 * j + 0][rr])) << (8 * j);
            hi |= f2fp4(bf2f(lt[q * 16 + 8 + 2 * j + 1][rr])) << (8 * j + 4);
        }
        w.x = lo; w.y = hi;
        *(uint2*)&XtT4[(size_t)(bl * 768 + rr) * 1024 + (n0 >> 1) + q * 8] = w;
    }
}

// ---------------------------------------------------------------------------
// 128^2-tile bf16 GEMM for A^2 (bf16 out -> a2sq temp).
__global__ __launch_bounds__(256, 2)
void gemm_bt_kernel(const u16* __restrict__ A0, const u16* __restrict__ B0, u16* __restrict__ C0,
                    const u16* __restrict__ A1p, const u16* __restrict__ B1p, u16* __restrict__ C1p,
                    int K, int lda, int ldb, int ldc) {
    const u16* A  = blockIdx.z ? A1p : A0;
    const u16* BT = blockIdx.z ? B1p : B0;
    u16* C        = blockIdx.z ? C1p : C0;

    __shared__ u16 lA[128 * 64];
    __shared__ u16 lB[128 * 64];

    int gx = gridDim.x;
    int nwg = gx * gridDim.y;
    int orig = blockIdx.y * gx + blockIdx.x;
    int swz = (orig & 7) * (nwg >> 3) + (orig >> 3);
    int by = swz / gx, bx = swz - by * gx;

    const int m0 = by * 128, n0 = bx * 128;
    const int tid = threadIdx.x;
    const int w = tid >> 6, l = tid & 63;
    const int wr = w >> 1, wc = w & 1;

    f32x4 acc[4][4] = {};

    const int srow = l >> 3;
    const int scol = ((l & 7) ^ srow) * 8;

    for (int kt = 0; kt < K; kt += 64) {
#pragma unroll
        for (int r = 0; r < 4; ++r) {
            int s = w * 4 + r;
            int row = s * 8 + srow;
            gload16(A + (size_t)(m0 + row) * lda + kt + scol, &lA[s * 512]);
        }
#pragma unroll
        for (int r = 0; r < 4; ++r) {
            int s = w * 4 + r;
            int row = s * 8 + srow;
            gload16(BT + (size_t)(n0 + row) * ldb + kt + scol, &lB[s * 512]);
        }
        __syncthreads();
#pragma unroll
        for (int kk = 0; kk < 2; ++kk) {
            bf16x8 af[4], bfr[4];
            const int cg = ((kk * 4 + (l >> 4)) ^ (l & 7)) * 8;
#pragma unroll
            for (int i = 0; i < 4; ++i)
                af[i] = *(const bf16x8*)&lA[(wr * 64 + i * 16 + (l & 15)) * 64 + cg];
#pragma unroll
            for (int j = 0; j < 4; ++j)
                bfr[j] = *(const bf16x8*)&lB[(wc * 64 + j * 16 + (l & 15)) * 64 + cg];
#pragma unroll
            for (int i = 0; i < 4; ++i)
#pragma unroll
                for (int j = 0; j < 4; ++j)
                    acc[i][j] = __builtin_amdgcn_mfma_f32_16x16x32_bf16(af[i], bfr[j], acc[i][j], 0, 0, 0);
        }
        __syncthreads();
    }

    const int lr = (l >> 4) * 4, lc = l & 15;
#pragma unroll
    for (int i = 0; i < 4; ++i) {
        int row = m0 + wr * 64 + i * 16 + lr;
#pragma unroll
        for (int j = 0; j < 4; ++j) {
            int col = n0 + wc * 64 + j * 16 + lc;
            u16* p = C + (size_t)row * ldc + col;
#pragma unroll
            for (int q = 0; q < 4; ++q)
                p[(size_t)q * ldc] = f2bf(acc[i][j][q]);
        }
    }
}

// ---------------------------------------------------------------------------
// 256^2-tile MX-fp4 GEMM. R4/R6/R7 skeleton unchanged: 128-B rows, same stage
// swizzle, same vmcnt(6) ledger, 4 phases/tile. K-tile = 256 fp4 (NT=8);
// per phase 16 MFMA (2 k-steps); frag = ONE b128 at slot (kk*4+h)^(r&7).
__device__ __forceinline__ void stage_half256(const u8* __restrict__ src, int ld,
                                              u8* lds, int kt, int tid) {
    int w8 = (tid >> 6) << 3;
    int l = tid & 63;
    int r = l >> 3;
#pragma unroll
    for (int iss = 0; iss < 2; ++iss) {
        int R = iss * 64 + w8 + r;
        gload16(src + (size_t)R * ld + kt + (((l & 7) ^ r) << 4),
                lds + (size_t)(iss * 64 + w8) * 128);
    }
}

__device__ __forceinline__ i32x4 ldfrag4(const u8* lds, int r, int slot) {
    return *(const i32x4*)&lds[(size_t)r * 128 + ((slot ^ (r & 7)) << 4)];
}

__device__ __forceinline__ i32x8 up8(i32x4 v) {
    i32x8 r = {v[0], v[1], v[2], v[3], 0, 0, 0, 0};
    return r;
}

#define MFMA4(ACC, AF, BF)                                                               \
    _Pragma("unroll")                                                                     \
    for (int kk = 0; kk < 2; ++kk)                                                        \
        _Pragma("unroll")                                                                 \
        for (int i = 0; i < 4; ++i)                                                       \
            _Pragma("unroll")                                                             \
            for (int j = 0; j < 2; ++j)                                                   \
                ACC[i][j] = __builtin_amdgcn_mfma_scale_f32_16x16x128_f8f6f4(             \
                    up8(AF[kk][i]), up8(BF[kk][j]), ACC[i][j], 4, 4, 0, 0x7F7F7F7F, 0, 0x7F7F7F7F);

__global__ __launch_bounds__(512, 2)
void gemm256_kernel(const u8* __restrict__ A, const u8* __restrict__ BT,
                    u16* __restrict__ C, int Kb, int lda, int ldb, int ldc) {
    __shared__ u8 lds8[2][2][256 * 128];   // [buf][A=0/B=1] : 128 KiB

    int gx = gridDim.x;
    int nwg = gx * gridDim.y;
    int orig = blockIdx.y * gx + blockIdx.x;
    int swz = (orig & 7) * (nwg >> 3) + (orig >> 3);
    int by = swz / gx, bx = swz - by * gx;

    const int m0 = by * 256, n0 = bx * 256;
    const int tid = threadIdx.x;
    const int w = tid >> 6, l = tid & 63;
    const int wr = w >> 2, wc = w & 3;      // 2 x 4 wave grid
    const int NT = Kb >> 7;                 // Kb bytes, 128 B/tile

    f32x4 acc[2][2][4][2] = {};             // [qm][qn][i][j]

    // prologue: tile 0 (4 halves) -> buf0; tile 1 {A0,A1,B0} -> buf1
    {
        stage_half256(A + (size_t)m0 * lda, lda, &lds8[0][0][0], 0, tid);
        stage_half256(A + (size_t)(m0 + 128) * lda, lda, &lds8[0][0][128 * 128], 0, tid);
        stage_half256(BT + (size_t)n0 * ldb, ldb, &lds8[0][1][0], 0, tid);
        stage_half256(BT + (size_t)(n0 + 128) * ldb, ldb, &lds8[0][1][128 * 128], 0, tid);
        if (NT > 1) {
            stage_half256(A + (size_t)m0 * lda, lda, &lds8[1][0][0], 128, tid);
            stage_half256(A + (size_t)(m0 + 128) * lda, lda, &lds8[1][0][128 * 128], 128, tid);
            stage_half256(BT + (size_t)n0 * ldb, ldb, &lds8[1][1][0], 128, tid);
            asm volatile("s_waitcnt vmcnt(6)" ::: "memory");
        } else {
            asm volatile("s_waitcnt vmcnt(0)" ::: "memory");
        }
        __builtin_amdgcn_s_barrier();
    }

    const int lm = l & 15;
    const int h = l >> 4;                   // k-quarter
    i32x4 af[2][4], b0[2][2], b1[2][2];

    for (int t = 0; t < NT; ++t) {
        const int cur = t & 1;
        u8* lA = lds8[cur][0];
        u8* lB = lds8[cur][1];
        const bool s1 = (t + 1 < NT);
        const bool s2 = (t + 2 < NT);
        const int kt1 = (t + 1) << 7;
        const int kt2 = (t + 2) << 7;

        // ---- phase 1: reads A(qm0)+B(qn0); stage B1(t+1) -> buf^1 ----
#pragma unroll
        for (int kk = 0; kk < 2; ++kk) {
#pragma unroll
            for (int i = 0; i < 4; ++i)
                af[kk][i] = ldfrag4(lA, wr * 128 + i * 16 + lm, kk * 4 + h);
#pragma unroll
            for (int j = 0; j < 2; ++j)
                b0[kk][j] = ldfrag4(lB, wc * 64 + j * 16 + lm, kk * 4 + h);
        }
        if (s1)
            stage_half256(BT + (size_t)(n0 + 128) * ldb, ldb, &lds8[cur ^ 1][1][128 * 128], kt1, tid);
        __builtin_amdgcn_s_barrier();
        __builtin_amdgcn_s_setprio(1);
        MFMA4(acc[0][0], af, b0);
        __builtin_amdgcn_s_setprio(0);
        __builtin_amdgcn_s_barrier();

        // ---- phase 2: reads B(qn1); stage A0(t+2) -> buf cur ----
#pragma unroll
        for (int kk = 0; kk < 2; ++kk)
#pragma unroll
            for (int j = 0; j < 2; ++j)
                b1[kk][j] = ldfrag4(lB, wc * 64 + 32 + j * 16 + lm, kk * 4 + h);
        if (s2)
            stage_half256(A + (size_t)m0 * lda, lda, lA, kt2, tid);
        __builtin_amdgcn_s_barrier();
        __builtin_amdgcn_s_setprio(1);
        MFMA4(acc[0][1], af, b1);
        __builtin_amdgcn_s_setprio(0);
        __builtin_amdgcn_s_barrier();

        // ---- phase 3: reads A(qm1); stage B0(t+2) -> buf cur ----
#pragma unroll
        for (int kk = 0; kk < 2; ++kk)
#pragma unroll
            for (int i = 0; i < 4; ++i)
                af[kk][i] = ldfrag4(lA, wr * 128 + 64 + i * 16 + lm, kk * 4 + h);
        if (s2)
            stage_half256(BT + (size_t)n0 * ldb, ldb, lB, kt2, tid);
        __builtin_amdgcn_s_barrier();
        __builtin_amdgcn_s_setprio(1);
        MFMA4(acc[1][0], af, b0);
        __builtin_amdgcn_s_setprio(0);
        __builtin_amdgcn_s_barrier();

        // ---- phase 4: MFMA q11; stage A1(t+2) -> buf cur; boundary ----
        __builtin_amdgcn_s_setprio(1);
        MFMA4(acc[1][1], af, b1);
        __builtin_amdgcn_s_setprio(0);

        if (s2)
            stage_half256(A + (size_t)(m0 + 128) * lda, lda, lA + 128 * 128, kt2, tid);
        if (s1) {
            if (s2) asm volatile("s_waitcnt vmcnt(6)" ::: "memory");
            else    asm volatile("s_waitcnt vmcnt(0)" ::: "memory");
            __builtin_amdgcn_s_barrier();
        }
    }

    // C/D layout (shape-determined): col = lane&15, row = (lane>>4)*4 + reg
    const int lr = (l >> 4) * 4, lc = l & 15;
#pragma unroll
    for (int qm = 0; qm < 2; ++qm)
#pragma unroll
        for (int i = 0; i < 4; ++i) {
            int row = m0 + wr * 128 + qm * 64 + i * 16 + lr;
#pragma unroll
            for (int qn = 0; qn < 2; ++qn)
#pragma unroll
                for (int j = 0; j < 2; ++j) {
                    int col = n0 + wc * 64 + qn * 32 + j * 16 + lc;
                    u16* p = C + (size_t)row * ldc + col;
#pragma unroll
                    for (int q = 0; q < 4; ++q)
                        p[(size_t)q * ldc] = f2bf(acc[qm][qn][i][j][q] * DSCALE);
                }
        }
}

// ---------------------------------------------------------------------------
// conv: uniform 5-hop bf16 loop over Y5 = [X0 ; Y].
__global__ __launch_bounds__(256, 2)
void conv_kernel(const u16* __restrict__ Y5, const u16* __restrict__ Wbf,
                 const float* __restrict__ bias, float* __restrict__ yout,
                 int b0, int Gb, int nPerBlk, int ldy) {
    __shared__ u16 lh[192 * 72];
    const int colsPerN = Gb * 12;
    const int n0 = blockIdx.x * nPerBlk;
    const int tid = threadIdx.x;
    const int w = tid >> 6, l = tid & 63;
    f32x4 acc[4][3] = {};

    for (int k = 0; k < 5; ++k) {
        __syncthreads();
        for (int it = tid; it < 1536; it += 256) {
            int e8 = it << 3;
            int c = e8 & 63;
            int jj = e8 >> 6;
            int nl = jj / colsPerN;
            int rem = jj - nl * colsPerN;
            const u16* src = Y5 + (size_t)(k * 2048 + n0 + nl) * ldy + rem * 64 + c;
            *(u16x8*)&lh[jj * 72 + c] = *(const u16x8*)src;
        }
        __syncthreads();
#pragma unroll
        for (int kk = 0; kk < 2; ++kk) {
            bf16x8 wf[4], hf[3];
#pragma unroll
            for (int i = 0; i < 4; ++i)
                wf[i] = *(const bf16x8*)&Wbf[(size_t)(k * 64 + i * 16 + (l & 15)) * 64 + kk * 32 + (l >> 4) * 8];
#pragma unroll
            for (int j = 0; j < 3; ++j)
                hf[j] = *(const bf16x8*)&lh[(w * 48 + j * 16 + (l & 15)) * 72 + kk * 32 + (l >> 4) * 8];
#pragma unroll
            for (int i = 0; i < 4; ++i)
#pragma unroll
                for (int j = 0; j < 3; ++j)
                    acc[i][j] = __builtin_amdgcn_mfma_f32_16x16x32_bf16(wf[i], hf[j], acc[i][j], 0, 0, 0);
        }
    }

    const int lr = (l >> 4) * 4, lc = l & 15;
#pragma unroll
    for (int j = 0; j < 3; ++j) {
        int jj = w * 48 + j * 16 + lc;
        int nl = jj / colsPerN;
        int rem = jj - nl * colsPerN;
        int bl = rem / 12;
        int t = rem - bl * 12;
#pragma unroll
        for (int i = 0; i < 4; ++i) {
#pragma unroll
            for (int q = 0; q < 4; ++q) {
                int o = i * 16 + lr + q;
                yout[((size_t)((b0 + bl) * 64 + o) * 2048 + (n0 + nl)) * 12 + t] = acc[i][j][q] + bias[o];
            }
        }
    }
}

// ---------------------------------------------------------------------------
extern "C" void kernel_launch(void* const* d_in, const int* in_sizes, int n_in,
                              void* d_out, int out_size, void* d_ws, size_t ws_size,
                              hipStream_t stream) {
    (void)in_sizes; (void)n_in; (void)out_size;
    const float* x  = (const float*)d_in[0];
    const float* A1 = (const float*)d_in[1];
    const float* A2 = (const float*)d_in[2];
    const float* W  = (const float*)d_in[3];
    const float* bs = (const float*)d_in[4];
    float* y = (float*)d_out;
    char* ws = (char*)d_ws;

    // workspace:
    //   [0, 8.39M)    Astack4 fp4 [8192][1024 B] (A*8192)
    //   [8.39M,+64K)  Wbf
    //   [CHUNK_OFF)   transient a1b,a2b,a1t,a2t (4x8.39M) + a2sq (16.8M),
    //                 then per-chunk: XtT4 | X0 | Y
    const size_t CHUNK_OFF = 8454144;
    u8* astack4 = (u8*)ws;
    u16* wbf = (u16*)(ws + 8388608);
    u16* a1b = (u16*)(ws + CHUNK_OFF);
    u16* a2b = a1b + (size_t)2048 * 2048;
    u16* a1t = a2b + (size_t)2048 * 2048;
    u16* a2t = a1t + (size_t)2048 * 2048;
    u16* a2sq = a2t + (size_t)2048 * 2048;   // [4096][2048] bf16

    // per-chunk bytes: XtT4 Gb*786432 + X0 Gb*3145728 + Y Gb*12582912
    size_t avail = ws_size > CHUNK_OFF ? ws_size - CHUNK_OFF : 0;
    int Gb = 16;
    while (Gb > 1 && (size_t)Gb * 16515072 > avail) Gb >>= 1;
    int ldy = Gb * 768;
    u8* xtT4 = (u8*)(ws + CHUNK_OFF);
    u16* x0  = (u16*)(xtT4 + (size_t)Gb * 768 * 1024);
    u16* Yc  = x0 + (size_t)2048 * ldy;     // GEMM C = hops 1..4
    int nPerBlk = 16 / Gb;

    cvt_w_kernel<<<80, 256, 0, stream>>>(W, wbf);
    cvt_a_kernel<<<2048, 256, 0, stream>>>(A1, A2, astack4, a1b, a2b, a1t, a2t);

    gemm_bt_kernel<<<dim3(16, 16, 2), 256, 0, stream>>>(
        a1b, a1t, a2sq,
        a2b, a2t, a2sq + (size_t)2048 * 2048,
        2048, 2048, 2048, 2048);
    pack_a2_kernel<<<4096, 256, 0, stream>>>(a2sq, astack4);

    for (int b0 = 0; b0 < 16; b0 += Gb) {
        pack_x_kernel<<<Gb * 64, 256, 0, stream>>>(x, xtT4, x0, b0, ldy);
        gemm256_kernel<<<dim3(ldy / 256, 32), 512, 0, stream>>>(
            astack4, xtT4, Yc, 1024, 1024, 1024, ldy);
        conv_kernel<<<128 * Gb, 256, 0, stream>>>(x0, wbf, bs, y, b0, Gb, nPerBlk, ldy);
    }
}

// Round 9
// 380.737 us; speedup vs baseline: 1.7291x; 1.0814x over previous
//
#include <hip/hip_runtime.h>

// SparseGraphConv: y = W @ concat([x, A1x, A1^2 x, A2 x, A2^2 x]) + b
// B=16, C=64, N=2048, T=12, C_OUT=64.
//
//   1. cvt_a:   A1,A2 f32 -> fp4(x8192) rows of Astack4 + fp4 transposed (a1t4/a2t4)
//   2. gemm_f4(z=2): A1^2, A2^2 (fp4 math, scale 2^-26) -> a2sq bf16 temp
//   3. pack_a2: a2sq bf16 -> fp4(x8192) rows of Astack4
//   4. pack_x:  x -> XtT4[(bl*12+t)*64+c][n] fp4 + X0[n][btc] bf16 (hop-0)
//   5. gemm_f4: Y = (Astack4 @ XtT4^T)/8192 -- 128^2 2-phase m97 structure
//               (R1-verified skeleton; 32 KiB LDS -> ~4 blocks/CU), MX-fp4
//               mfma_scale_f32_16x16x128_f8f6f4, fragment addressing verified in R8.
//   6. conv:    uniform 5-hop bf16 read from [X0 ; Y]

typedef __attribute__((ext_vector_type(8))) __bf16 bf16x8;
typedef __attribute__((ext_vector_type(4))) float f32x4;
typedef __attribute__((ext_vector_type(4))) int i32x4;
typedef __attribute__((ext_vector_type(8))) int i32x8;
typedef __attribute__((ext_vector_type(8))) unsigned short u16x8;
typedef unsigned short u16;
typedef unsigned int u32;
typedef unsigned char u8;

__device__ __forceinline__ u16 f2bf(float f) {
    u32 u = __float_as_uint(f);
    u32 r = u + 0x7FFFu + ((u >> 16) & 1u);   // round-to-nearest-even
    return (u16)(r >> 16);
}

__device__ __forceinline__ float bf2f(u16 v) {
    return __uint_as_float((u32)v << 16);
}

// e2m1 nibble encode, round-to-nearest; levels {0,.5,1,1.5,2,3,4,6}
__device__ __forceinline__ u32 f2fp4(float f) {
    u32 s = (__float_as_uint(f) >> 31) << 3;
    float m = fabsf(f);
    u32 c;
    if      (m < 0.25f) c = 0;
    else if (m < 0.75f) c = 1;
    else if (m < 1.25f) c = 2;
    else if (m < 1.75f) c = 3;
    else if (m < 2.5f)  c = 4;
    else if (m < 3.5f)  c = 5;
    else if (m < 5.0f)  c = 6;
    else                c = 7;
    return s | c;
}

__device__ __forceinline__ void gload16(const void* g, void* l) {
    __builtin_amdgcn_global_load_lds((const __attribute__((address_space(1))) void*)g,
                                     (__attribute__((address_space(3))) void*)l, 16, 0, 0);
}

__device__ __forceinline__ i32x8 up8(i32x4 v) {
    i32x8 r = {v[0], v[1], v[2], v[3], 0, 0, 0, 0};
    return r;
}

#define ASCALE 8192.f

// ---------------------------------------------------------------------------
__global__ __launch_bounds__(256)
void cvt_w_kernel(const float* __restrict__ W, u16* __restrict__ wbf) {
    int i = blockIdx.x * 256 + threadIdx.x;
    if (i < 5 * 64 * 64) {
        int c = i & 63;
        int o = (i >> 6) & 63;
        int k = i >> 12;
        wbf[i] = f2bf(W[o * 320 + k * 64 + c]);
    }
}

// ---------------------------------------------------------------------------
// A1,A2 f32 -> fp4(x8192) direct rows of Astack4 (0..2047 / 4096..6143)
//           -> fp4(x8192) transposed (a1t4/a2t4) for the A^2 GEMM BT operand
__global__ __launch_bounds__(256)
void cvt_a_kernel(const float* __restrict__ A1, const float* __restrict__ A2,
                  u8* __restrict__ astack4, u8* __restrict__ a1t4, u8* __restrict__ a2t4) {
    __shared__ float lt[64][65];
    int bid = blockIdx.x;
    int mat = bid >> 10;
    int ti = bid & 1023;
    int tr = (ti >> 5) << 6;
    int tc = (ti & 31) << 6;
    const float* src = mat ? A2 : A1;
    u8* dst4 = astack4 + (size_t)(mat ? 4096 : 0) * 1024;
    u8* dstT4 = mat ? a2t4 : a1t4;
    int tid = threadIdx.x;
    int rr = tid >> 4;
    int cc = (tid & 15) << 2;
#pragma unroll
    for (int p = 0; p < 4; ++p) {
        int row = p * 16 + rr;
        float4 v = *(const float4*)&src[(size_t)(tr + row) * 2048 + tc + cc];
        u16 w4 = (u16)(f2fp4(v.x * ASCALE) | (f2fp4(v.y * ASCALE) << 4) |
                       (f2fp4(v.z * ASCALE) << 8) | (f2fp4(v.w * ASCALE) << 12));
        *(u16*)&dst4[(size_t)(tr + row) * 1024 + ((tc + cc) >> 1)] = w4;
        lt[row][cc + 0] = v.x; lt[row][cc + 1] = v.y;
        lt[row][cc + 2] = v.z; lt[row][cc + 3] = v.w;
    }
    __syncthreads();
#pragma unroll
    for (int p = 0; p < 4; ++p) {
        int row = p * 16 + rr;   // row of transposed tile = original col
        u16 w4 = (u16)(f2fp4(lt[cc + 0][row] * ASCALE) |
                       (f2fp4(lt[cc + 1][row] * ASCALE) << 4) |
                       (f2fp4(lt[cc + 2][row] * ASCALE) << 8) |
                       (f2fp4(lt[cc + 3][row] * ASCALE) << 12));
        *(u16*)&dstT4[(size_t)(tc + row) * 1024 + ((tr + cc) >> 1)] = w4;
    }
}

// ---------------------------------------------------------------------------
// a2sq bf16 [4096][2048] (A1^2 ; A2^2) -> fp4(x8192) Astack4 rows 2048.. / 6144..
__global__ __launch_bounds__(256)
void pack_a2_kernel(const u16* __restrict__ a2sq, u8* __restrict__ astack4) {
    int i = blockIdx.x * 256 + threadIdx.x;   // 4096 blocks: 8 elems/thread
    int e = i << 3;
    int r = e >> 11, c = e & 2047;
    const u16* s = a2sq + ((size_t)r << 11) + c;
    u16x8 v = *(const u16x8*)s;
    u32 w = 0;
#pragma unroll
    for (int j = 0; j < 8; ++j)
        w |= f2fp4(bf2f(v[j]) * ASCALE) << (4 * j);
    int row = (r < 2048) ? (2048 + r) : (4096 + r);
    *(u32*)&astack4[(size_t)row * 1024 + (c >> 1)] = w;
}

// ---------------------------------------------------------------------------
// pack_x: block = 32 nodes x one local batch bl; LDS [32][768(+8)] bf16 tile.
//   XtT4[bl*768 + (t*64+c)][n]  fp4 (GEMM B^T operand, n pairs per byte)
//   X0 [n][bl*768 + t*64 + c]   bf16 (hop-0 plane in Y layout)
__global__ __launch_bounds__(256)
void pack_x_kernel(const float* __restrict__ x, u8* __restrict__ XtT4,
                   u16* __restrict__ X0, int b0, int ldy) {
    __shared__ u16 lt[32][776];
    const int bl = blockIdx.x >> 6;
    const int n0 = (blockIdx.x & 63) << 5;
    const int tid = threadIdx.x;
    const int ng = tid & 31, c8 = tid >> 5;
#pragma unroll
    for (int it = 0; it < 8; ++it) {
        int c = it * 8 + c8;
        const float* src = x + ((size_t)((b0 + bl) * 64 + c) * 2048 + n0 + ng) * 12;
        float4 v0 = *(const float4*)(src + 0);
        float4 v1 = *(const float4*)(src + 4);
        float4 v2 = *(const float4*)(src + 8);
        float vv[12];
        *(float4*)&vv[0] = v0; *(float4*)&vv[4] = v1; *(float4*)&vv[8] = v2;
#pragma unroll
        for (int t = 0; t < 12; ++t)
            lt[ng][t * 64 + c] = f2bf(vv[t]);
    }
    __syncthreads();
    for (int i = tid; i < 3072; i += 256) {
        int r = i / 96, ch = i - r * 96;
        *(u16x8*)&X0[(size_t)(n0 + r) * ldy + bl * 768 + ch * 8] =
            *(const u16x8*)&lt[r][ch * 8];
    }
    // XtT4: thread packs 16 n-values -> 8 bytes
    for (int i = tid; i < 1536; i += 256) {
        int rr = i >> 1, q = i & 1;
        uint2 w;
        u32 lo = 0, hi = 0;
#pragma unroll
        for (int j = 0; j < 4; ++j) {
            lo |= f2fp4(bf2f(lt[q * 16 + 2 * j + 0][rr])) << (8 * j);
            lo |= f2fp4(bf2f(lt[q * 16 + 2 * j + 1][rr])) << (8 * j + 4);
            hi |= f2fp4(bf2f(lt[q * 16 + 8 + 2 * j + 0][rr])) << (8 * j);
            hi |= f2fp4(bf2f(lt[q * 16 + 8 + 2 * j + 1][rr])) << (8 * j + 4);
        }
        w.x = lo; w.y = hi;
        *(uint2*)&XtT4[(size_t)(bl * 768 + rr) * 1024 + (n0 >> 1) + q * 8] = w;
    }
}

// ---------------------------------------------------------------------------
// Unified 128^2-tile MX-fp4 GEMM (m97/R1 2-phase structure, 32 KiB LDS ->
// high occupancy; cross-block overlap hides the per-tile drain).
// C[M,N] = oscale * (A @ BT^T); A,BT fp4 rows of 128 B (256 elems); C bf16.
// Fragment addressing = R8-verified: stage swizzle phys-slot (l&7)^row8,
// read slot (kk*4+(l>>4))^(r&7); MFMA = scale_f32_16x16x128_f8f6f4 (fp4).
// gridDim.z selects pointer set (dual launch for A1^2/A2^2).
__global__ __launch_bounds__(256, 4)
void gemm_f4_kernel(const u8* __restrict__ A0, const u8* __restrict__ B0, u16* __restrict__ C0,
                    const u8* __restrict__ A1p, const u8* __restrict__ B1p, u16* __restrict__ C1p,
                    int Kb, int lda, int ldb, int ldc, float oscale) {
    const u8* A  = blockIdx.z ? A1p : A0;
    const u8* BT = blockIdx.z ? B1p : B0;
    u16* C       = blockIdx.z ? C1p : C0;

    __shared__ u8 lA[128 * 128];
    __shared__ u8 lB[128 * 128];

    int gx = gridDim.x;
    int nwg = gx * gridDim.y;
    int orig = blockIdx.y * gx + blockIdx.x;
    int swz = (orig & 7) * (nwg >> 3) + (orig >> 3);
    int by = swz / gx, bx = swz - by * gx;

    const int m0 = by * 128, n0 = bx * 128;
    const int tid = threadIdx.x;
    const int w = tid >> 6, l = tid & 63;
    const int wr = w >> 1, wc = w & 1;

    f32x4 acc[4][4] = {};

    const int srow = l >> 3;
    const int scol = ((l & 7) ^ srow) << 4;   // byte offset within 128-B row

    for (int kt = 0; kt < Kb; kt += 128) {
#pragma unroll
        for (int r = 0; r < 4; ++r) {
            int s = w * 4 + r;
            int row = s * 8 + srow;
            gload16(A + (size_t)(m0 + row) * lda + kt + scol, &lA[s * 1024]);
        }
#pragma unroll
        for (int r = 0; r < 4; ++r) {
            int s = w * 4 + r;
            int row = s * 8 + srow;
            gload16(BT + (size_t)(n0 + row) * ldb + kt + scol, &lB[s * 1024]);
        }
        __syncthreads();   // compiler emits s_waitcnt vmcnt(0) before s_barrier
#pragma unroll
        for (int kk = 0; kk < 2; ++kk) {
            i32x4 af[4], bfr[4];
            const int slot = kk * 4 + (l >> 4);
#pragma unroll
            for (int i = 0; i < 4; ++i) {
                int r = wr * 64 + i * 16 + (l & 15);
                af[i] = *(const i32x4*)&lA[(size_t)r * 128 + ((slot ^ (r & 7)) << 4)];
            }
#pragma unroll
            for (int j = 0; j < 4; ++j) {
                int r = wc * 64 + j * 16 + (l & 15);
                bfr[j] = *(const i32x4*)&lB[(size_t)r * 128 + ((slot ^ (r & 7)) << 4)];
            }
#pragma unroll
            for (int i = 0; i < 4; ++i)
#pragma unroll
                for (int j = 0; j < 4; ++j)
                    acc[i][j] = __builtin_amdgcn_mfma_scale_f32_16x16x128_f8f6f4(
                        up8(af[i]), up8(bfr[j]), acc[i][j], 4, 4, 0, 0x7F7F7F7F, 0, 0x7F7F7F7F);
        }
        __syncthreads();
    }

    // C/D layout: col = lane&15, row = (lane>>4)*4 + reg
    const int lr = (l >> 4) * 4, lc = l & 15;
#pragma unroll
    for (int i = 0; i < 4; ++i) {
        int row = m0 + wr * 64 + i * 16 + lr;
#pragma unroll
        for (int j = 0; j < 4; ++j) {
            int col = n0 + wc * 64 + j * 16 + lc;
            u16* p = C + (size_t)row * ldc + col;
#pragma unroll
            for (int q = 0; q < 4; ++q)
                p[(size_t)q * ldc] = f2bf(acc[i][j][q] * oscale);
        }
    }
}

// ---------------------------------------------------------------------------
// conv: uniform 5-hop bf16 loop over Y5 = [X0 ; Y].
__global__ __launch_bounds__(256, 2)
void conv_kernel(const u16* __restrict__ Y5, const u16* __restrict__ Wbf,
                 const float* __restrict__ bias, float* __restrict__ yout,
                 int b0, int Gb, int nPerBlk, int ldy) {
    __shared__ u16 lh[192 * 72];
    const int colsPerN = Gb * 12;
    const int n0 = blockIdx.x * nPerBlk;
    const int tid = threadIdx.x;
    const int w = tid >> 6, l = tid & 63;
    f32x4 acc[4][3] = {};

    for (int k = 0; k < 5; ++k) {
        __syncthreads();
        for (int it = tid; it < 1536; it += 256) {
            int e8 = it << 3;
            int c = e8 & 63;
            int jj = e8 >> 6;
            int nl = jj / colsPerN;
            int rem = jj - nl * colsPerN;
            const u16* src = Y5 + (size_t)(k * 2048 + n0 + nl) * ldy + rem * 64 + c;
            *(u16x8*)&lh[jj * 72 + c] = *(const u16x8*)src;
        }
        __syncthreads();
#pragma unroll
        for (int kk = 0; kk < 2; ++kk) {
            bf16x8 wf[4], hf[3];
#pragma unroll
            for (int i = 0; i < 4; ++i)
                wf[i] = *(const bf16x8*)&Wbf[(size_t)(k * 64 + i * 16 + (l & 15)) * 64 + kk * 32 + (l >> 4) * 8];
#pragma unroll
            for (int j = 0; j < 3; ++j)
                hf[j] = *(const bf16x8*)&lh[(w * 48 + j * 16 + (l & 15)) * 72 + kk * 32 + (l >> 4) * 8];
#pragma unroll
            for (int i = 0; i < 4; ++i)
#pragma unroll
                for (int j = 0; j < 3; ++j)
                    acc[i][j] = __builtin_amdgcn_mfma_f32_16x16x32_bf16(wf[i], hf[j], acc[i][j], 0, 0, 0);
        }
    }

    const int lr = (l >> 4) * 4, lc = l & 15;
#pragma unroll
    for (int j = 0; j < 3; ++j) {
        int jj = w * 48 + j * 16 + lc;
        int nl = jj / colsPerN;
        int rem = jj - nl * colsPerN;
        int bl = rem / 12;
        int t = rem - bl * 12;
#pragma unroll
        for (int i = 0; i < 4; ++i) {
#pragma unroll
            for (int q = 0; q < 4; ++q) {
                int o = i * 16 + lr + q;
                yout[((size_t)((b0 + bl) * 64 + o) * 2048 + (n0 + nl)) * 12 + t] = acc[i][j][q] + bias[o];
            }
        }
    }
}

// ---------------------------------------------------------------------------
extern "C" void kernel_launch(void* const* d_in, const int* in_sizes, int n_in,
                              void* d_out, int out_size, void* d_ws, size_t ws_size,
                              hipStream_t stream) {
    (void)in_sizes; (void)n_in; (void)out_size;
    const float* x  = (const float*)d_in[0];
    const float* A1 = (const float*)d_in[1];
    const float* A2 = (const float*)d_in[2];
    const float* W  = (const float*)d_in[3];
    const float* bs = (const float*)d_in[4];
    float* y = (float*)d_out;
    char* ws = (char*)d_ws;

    // workspace:
    //   [0, 8.39M)    Astack4 fp4 [8192][1024 B] (A*8192)
    //   [8.39M,+64K)  Wbf
    //   [CHUNK_OFF)   transient a1t4,a2t4 (2x2.1M) + a2sq bf16 (16.8M),
    //                 then per-chunk: XtT4 | X0 | Y
    const size_t CHUNK_OFF = 8454144;
    u8* astack4 = (u8*)ws;
    u16* wbf = (u16*)(ws + 8388608);
    u8* a1t4 = (u8*)(ws + CHUNK_OFF);
    u8* a2t4 = a1t4 + (size_t)2048 * 1024;
    u16* a2sq = (u16*)(a2t4 + (size_t)2048 * 1024);   // [4096][2048] bf16

    // per-chunk bytes: XtT4 Gb*786432 + X0 Gb*3145728 + Y Gb*12582912
    size_t avail = ws_size > CHUNK_OFF ? ws_size - CHUNK_OFF : 0;
    int Gb = 16;
    while (Gb > 1 && (size_t)Gb * 16515072 > avail) Gb >>= 1;
    int ldy = Gb * 768;
    u8* xtT4 = (u8*)(ws + CHUNK_OFF);
    u16* x0  = (u16*)(xtT4 + (size_t)Gb * 768 * 1024);
    u16* Yc  = x0 + (size_t)2048 * ldy;     // GEMM C = hops 1..4
    int nPerBlk = 16 / Gb;

    cvt_w_kernel<<<80, 256, 0, stream>>>(W, wbf);
    cvt_a_kernel<<<2048, 256, 0, stream>>>(A1, A2, astack4, a1t4, a2t4);

    // A1^2, A2^2 in fp4 (dual launch); acc = A^2 * 2^26 -> bf16 * 2^-26
    gemm_f4_kernel<<<dim3(16, 16, 2), 256, 0, stream>>>(
        astack4, a1t4, a2sq,
        astack4 + (size_t)4096 * 1024, a2t4, a2sq + (size_t)2048 * 2048,
        1024, 1024, 1024, 2048, 1.f / 67108864.f);
    pack_a2_kernel<<<4096, 256, 0, stream>>>(a2sq, astack4);

    for (int b0 = 0; b0 < 16; b0 += Gb) {
        pack_x_kernel<<<Gb * 64, 256, 0, stream>>>(x, xtT4, x0, b0, ldy);
        gemm_f4_kernel<<<dim3(ldy / 128, 64, 1), 256, 0, stream>>>(
            astack4, xtT4, Yc, astack4, xtT4, Yc,
            1024, 1024, 1024, ldy, 1.f / 8192.f);
        conv_kernel<<<128 * Gb, 256, 0, stream>>>(x0, wbf, bs, y, b0, Gb, nPerBlk, ldy);
    }
}

// Round 10
// 337.053 us; speedup vs baseline: 1.9532x; 1.1296x over previous
//
#include <hip/hip_runtime.h>

// SparseGraphConv: y = W @ concat([x, A1x, A1^2 x, A2 x, A2^2 x]) + b
// B=16, C=64, N=2048, T=12, C_OUT=64.
//
//   1. cvt_a:   A1,A2 f32 -> fp4(x8192) rows of Astack4 + fp4 transposed (a1t4/a2t4)
//   2. gemm_f4(z=2): A1^2, A2^2 (fp4 math, scale 2^-26) -> a2sq bf16 temp
//   3. pack_a2: a2sq bf16 -> fp4(x8192) rows of Astack4
//   4. pack_x:  x -> XtT4[(bl*12+t)*64+c][n] fp4 + X0[n][btc] bf16 (hop-0)
//   5. gemm_f4: Y = (Astack4 @ XtT4^T)/8192 -- 128^2 2-phase m97 structure, MX-fp4
//   6. conv:    uniform 5-hop bf16 read from [X0 ; Y]; block = (16 nodes x 1 batch)
//               so y-writes are 64-B coalesced (n*12+t contiguous for fixed b,o)

typedef __attribute__((ext_vector_type(8))) __bf16 bf16x8;
typedef __attribute__((ext_vector_type(4))) float f32x4;
typedef __attribute__((ext_vector_type(4))) int i32x4;
typedef __attribute__((ext_vector_type(8))) int i32x8;
typedef __attribute__((ext_vector_type(8))) unsigned short u16x8;
typedef unsigned short u16;
typedef unsigned int u32;
typedef unsigned char u8;

__device__ __forceinline__ u16 f2bf(float f) {
    u32 u = __float_as_uint(f);
    u32 r = u + 0x7FFFu + ((u >> 16) & 1u);   // round-to-nearest-even
    return (u16)(r >> 16);
}

__device__ __forceinline__ float bf2f(u16 v) {
    return __uint_as_float((u32)v << 16);
}

// e2m1 nibble encode, round-to-nearest; levels {0,.5,1,1.5,2,3,4,6}
__device__ __forceinline__ u32 f2fp4(float f) {
    u32 s = (__float_as_uint(f) >> 31) << 3;
    float m = fabsf(f);
    u32 c;
    if      (m < 0.25f) c = 0;
    else if (m < 0.75f) c = 1;
    else if (m < 1.25f) c = 2;
    else if (m < 1.75f) c = 3;
    else if (m < 2.5f)  c = 4;
    else if (m < 3.5f)  c = 5;
    else if (m < 5.0f)  c = 6;
    else                c = 7;
    return s | c;
}

__device__ __forceinline__ void gload16(const void* g, void* l) {
    __builtin_amdgcn_global_load_lds((const __attribute__((address_space(1))) void*)g,
                                     (__attribute__((address_space(3))) void*)l, 16, 0, 0);
}

__device__ __forceinline__ i32x8 up8(i32x4 v) {
    i32x8 r = {v[0], v[1], v[2], v[3], 0, 0, 0, 0};
    return r;
}

#define ASCALE 8192.f

// ---------------------------------------------------------------------------
__global__ __launch_bounds__(256)
void cvt_w_kernel(const float* __restrict__ W, u16* __restrict__ wbf) {
    int i = blockIdx.x * 256 + threadIdx.x;
    if (i < 5 * 64 * 64) {
        int c = i & 63;
        int o = (i >> 6) & 63;
        int k = i >> 12;
        wbf[i] = f2bf(W[o * 320 + k * 64 + c]);
    }
}

// ---------------------------------------------------------------------------
// A1,A2 f32 -> fp4(x8192) direct rows of Astack4 (0..2047 / 4096..6143)
//           -> fp4(x8192) transposed (a1t4/a2t4) for the A^2 GEMM BT operand
__global__ __launch_bounds__(256)
void cvt_a_kernel(const float* __restrict__ A1, const float* __restrict__ A2,
                  u8* __restrict__ astack4, u8* __restrict__ a1t4, u8* __restrict__ a2t4) {
    __shared__ float lt[64][65];
    int bid = blockIdx.x;
    int mat = bid >> 10;
    int ti = bid & 1023;
    int tr = (ti >> 5) << 6;
    int tc = (ti & 31) << 6;
    const float* src = mat ? A2 : A1;
    u8* dst4 = astack4 + (size_t)(mat ? 4096 : 0) * 1024;
    u8* dstT4 = mat ? a2t4 : a1t4;
    int tid = threadIdx.x;
    int rr = tid >> 4;
    int cc = (tid & 15) << 2;
#pragma unroll
    for (int p = 0; p < 4; ++p) {
        int row = p * 16 + rr;
        float4 v = *(const float4*)&src[(size_t)(tr + row) * 2048 + tc + cc];
        u16 w4 = (u16)(f2fp4(v.x * ASCALE) | (f2fp4(v.y * ASCALE) << 4) |
                       (f2fp4(v.z * ASCALE) << 8) | (f2fp4(v.w * ASCALE) << 12));
        *(u16*)&dst4[(size_t)(tr + row) * 1024 + ((tc + cc) >> 1)] = w4;
        lt[row][cc + 0] = v.x; lt[row][cc + 1] = v.y;
        lt[row][cc + 2] = v.z; lt[row][cc + 3] = v.w;
    }
    __syncthreads();
#pragma unroll
    for (int p = 0; p < 4; ++p) {
        int row = p * 16 + rr;   // row of transposed tile = original col
        u16 w4 = (u16)(f2fp4(lt[cc + 0][row] * ASCALE) |
                       (f2fp4(lt[cc + 1][row] * ASCALE) << 4) |
                       (f2fp4(lt[cc + 2][row] * ASCALE) << 8) |
                       (f2fp4(lt[cc + 3][row] * ASCALE) << 12));
        *(u16*)&dstT4[(size_t)(tc + row) * 1024 + ((tr + cc) >> 1)] = w4;
    }
}

// ---------------------------------------------------------------------------
// a2sq bf16 [4096][2048] (A1^2 ; A2^2) -> fp4(x8192) Astack4 rows 2048.. / 6144..
__global__ __launch_bounds__(256)
void pack_a2_kernel(const u16* __restrict__ a2sq, u8* __restrict__ astack4) {
    int i = blockIdx.x * 256 + threadIdx.x;   // 4096 blocks: 8 elems/thread
    int e = i << 3;
    int r = e >> 11, c = e & 2047;
    const u16* s = a2sq + ((size_t)r << 11) + c;
    u16x8 v = *(const u16x8*)s;
    u32 w = 0;
#pragma unroll
    for (int j = 0; j < 8; ++j)
        w |= f2fp4(bf2f(v[j]) * ASCALE) << (4 * j);
    int row = (r < 2048) ? (2048 + r) : (4096 + r);
    *(u32*)&astack4[(size_t)row * 1024 + (c >> 1)] = w;
}

// ---------------------------------------------------------------------------
// pack_x: block = 32 nodes x one local batch bl; LDS [32][768(+8)] bf16 tile.
//   XtT4[bl*768 + (t*64+c)][n]  fp4 (GEMM B^T operand, n pairs per byte)
//   X0 [n][bl*768 + t*64 + c]   bf16 (hop-0 plane in Y layout)
__global__ __launch_bounds__(256)
void pack_x_kernel(const float* __restrict__ x, u8* __restrict__ XtT4,
                   u16* __restrict__ X0, int b0, int ldy) {
    __shared__ u16 lt[32][776];
    const int bl = blockIdx.x >> 6;
    const int n0 = (blockIdx.x & 63) << 5;
    const int tid = threadIdx.x;
    const int ng = tid & 31, c8 = tid >> 5;
#pragma unroll
    for (int it = 0; it < 8; ++it) {
        int c = it * 8 + c8;
        const float* src = x + ((size_t)((b0 + bl) * 64 + c) * 2048 + n0 + ng) * 12;
        float4 v0 = *(const float4*)(src + 0);
        float4 v1 = *(const float4*)(src + 4);
        float4 v2 = *(const float4*)(src + 8);
        float vv[12];
        *(float4*)&vv[0] = v0; *(float4*)&vv[4] = v1; *(float4*)&vv[8] = v2;
#pragma unroll
        for (int t = 0; t < 12; ++t)
            lt[ng][t * 64 + c] = f2bf(vv[t]);
    }
    __syncthreads();
    for (int i = tid; i < 3072; i += 256) {
        int r = i / 96, ch = i - r * 96;
        *(u16x8*)&X0[(size_t)(n0 + r) * ldy + bl * 768 + ch * 8] =
            *(const u16x8*)&lt[r][ch * 8];
    }
    // XtT4: thread packs 16 n-values -> 8 bytes
    for (int i = tid; i < 1536; i += 256) {
        int rr = i >> 1, q = i & 1;
        uint2 w;
        u32 lo = 0, hi = 0;
#pragma unroll
        for (int j = 0; j < 4; ++j) {
            lo |= f2fp4(bf2f(lt[q * 16 + 2 * j + 0][rr])) << (8 * j);
            lo |= f2fp4(bf2f(lt[q * 16 + 2 * j + 1][rr])) << (8 * j + 4);
            hi |= f2fp4(bf2f(lt[q * 16 + 8 + 2 * j + 0][rr])) << (8 * j);
            hi |= f2fp4(bf2f(lt[q * 16 + 8 + 2 * j + 1][rr])) << (8 * j + 4);
        }
        w.x = lo; w.y = hi;
        *(uint2*)&XtT4[(size_t)(bl * 768 + rr) * 1024 + (n0 >> 1) + q * 8] = w;
    }
}

// ---------------------------------------------------------------------------
// Unified 128^2-tile MX-fp4 GEMM (m97/R1 2-phase structure; R8-verified
// fragment addressing; 32 KiB LDS -> ~4 blocks/CU).
__global__ __launch_bounds__(256, 4)
void gemm_f4_kernel(const u8* __restrict__ A0, const u8* __restrict__ B0, u16* __restrict__ C0,
                    const u8* __restrict__ A1p, const u8* __restrict__ B1p, u16* __restrict__ C1p,
                    int Kb, int lda, int ldb, int ldc, float oscale) {
    const u8* A  = blockIdx.z ? A1p : A0;
    const u8* BT = blockIdx.z ? B1p : B0;
    u16* C       = blockIdx.z ? C1p : C0;

    __shared__ u8 lA[128 * 128];
    __shared__ u8 lB[128 * 128];

    int gx = gridDim.x;
    int nwg = gx * gridDim.y;
    int orig = blockIdx.y * gx + blockIdx.x;
    int swz = (orig & 7) * (nwg >> 3) + (orig >> 3);
    int by = swz / gx, bx = swz - by * gx;

    const int m0 = by * 128, n0 = bx * 128;
    const int tid = threadIdx.x;
    const int w = tid >> 6, l = tid & 63;
    const int wr = w >> 1, wc = w & 1;

    f32x4 acc[4][4] = {};

    const int srow = l >> 3;
    const int scol = ((l & 7) ^ srow) << 4;   // byte offset within 128-B row

    for (int kt = 0; kt < Kb; kt += 128) {
#pragma unroll
        for (int r = 0; r < 4; ++r) {
            int s = w * 4 + r;
            int row = s * 8 + srow;
            gload16(A + (size_t)(m0 + row) * lda + kt + scol, &lA[s * 1024]);
        }
#pragma unroll
        for (int r = 0; r < 4; ++r) {
            int s = w * 4 + r;
            int row = s * 8 + srow;
            gload16(BT + (size_t)(n0 + row) * ldb + kt + scol, &lB[s * 1024]);
        }
        __syncthreads();
#pragma unroll
        for (int kk = 0; kk < 2; ++kk) {
            i32x4 af[4], bfr[4];
            const int slot = kk * 4 + (l >> 4);
#pragma unroll
            for (int i = 0; i < 4; ++i) {
                int r = wr * 64 + i * 16 + (l & 15);
                af[i] = *(const i32x4*)&lA[(size_t)r * 128 + ((slot ^ (r & 7)) << 4)];
            }
#pragma unroll
            for (int j = 0; j < 4; ++j) {
                int r = wc * 64 + j * 16 + (l & 15);
                bfr[j] = *(const i32x4*)&lB[(size_t)r * 128 + ((slot ^ (r & 7)) << 4)];
            }
#pragma unroll
            for (int i = 0; i < 4; ++i)
#pragma unroll
                for (int j = 0; j < 4; ++j)
                    acc[i][j] = __builtin_amdgcn_mfma_scale_f32_16x16x128_f8f6f4(
                        up8(af[i]), up8(bfr[j]), acc[i][j], 4, 4, 0, 0x7F7F7F7F, 0, 0x7F7F7F7F);
        }
        __syncthreads();
    }

    // C/D layout: col = lane&15, row = (lane>>4)*4 + reg
    const int lr = (l >> 4) * 4, lc = l & 15;
#pragma unroll
    for (int i = 0; i < 4; ++i) {
        int row = m0 + wr * 64 + i * 16 + lr;
#pragma unroll
        for (int j = 0; j < 4; ++j) {
            int col = n0 + wc * 64 + j * 16 + lc;
            u16* p = C + (size_t)row * ldc + col;
#pragma unroll
            for (int q = 0; q < 4; ++q)
                p[(size_t)q * ldc] = f2bf(acc[i][j][q] * oscale);
        }
    }
}

// ---------------------------------------------------------------------------
// conv: uniform 5-hop bf16 loop over Y5 = [X0 ; Y].
// Block = 16 nodes x ONE batch b (grid 128 x Gb): cols jj = nl*12 + t (192),
// rows = o (64). y address for fixed (b,o) is contiguous in n*12+t, so the
// epilogue writes 64-B coalesced segments (16 lanes x f32, jj-contiguous).
__global__ __launch_bounds__(256, 2)
void conv_kernel(const u16* __restrict__ Y5, const u16* __restrict__ Wbf,
                 const float* __restrict__ bias, float* __restrict__ yout,
                 int b0, int ldy) {
    __shared__ u16 lh[192 * 72];
    const int n0 = blockIdx.x << 4;          // 16 nodes per block
    const int bl = blockIdx.y;               // chunk-local batch
    const int b = b0 + bl;
    const int tid = threadIdx.x;
    const int w = tid >> 6, l = tid & 63;
    f32x4 acc[4][3] = {};

    for (int k = 0; k < 5; ++k) {
        __syncthreads();
        for (int it = tid; it < 1536; it += 256) {
            int e8 = it << 3;
            int c = e8 & 63;
            int jj = e8 >> 6;
            int nl = jj / 12;
            int t = jj - nl * 12;
            const u16* src = Y5 + (size_t)(k * 2048 + n0 + nl) * ldy + bl * 768 + t * 64 + c;
            *(u16x8*)&lh[jj * 72 + c] = *(const u16x8*)src;
        }
        __syncthreads();
#pragma unroll
        for (int kk = 0; kk < 2; ++kk) {
            bf16x8 wf[4], hf[3];
#pragma unroll
            for (int i = 0; i < 4; ++i)
                wf[i] = *(const bf16x8*)&Wbf[(size_t)(k * 64 + i * 16 + (l & 15)) * 64 + kk * 32 + (l >> 4) * 8];
#pragma unroll
            for (int j = 0; j < 3; ++j)
                hf[j] = *(const bf16x8*)&lh[(w * 48 + j * 16 + (l & 15)) * 72 + kk * 32 + (l >> 4) * 8];
#pragma unroll
            for (int i = 0; i < 4; ++i)
#pragma unroll
                for (int j = 0; j < 3; ++j)
                    acc[i][j] = __builtin_amdgcn_mfma_f32_16x16x32_bf16(wf[i], hf[j], acc[i][j], 0, 0, 0);
        }
    }

    // write: y[(b*64+o)*24576 + n0*12 + jj]; per (i,j,q): 16 lanes contiguous
    const int lr = (l >> 4) * 4, lc = l & 15;
    float* ybase = yout + (size_t)b * 64 * 24576 + (size_t)n0 * 12;
#pragma unroll
    for (int i = 0; i < 4; ++i) {
#pragma unroll
        for (int q = 0; q < 4; ++q) {
            int o = i * 16 + lr + q;
            float bv = bias[o];
            float* yo = ybase + (size_t)o * 24576;
#pragma unroll
            for (int j = 0; j < 3; ++j) {
                int jj = w * 48 + j * 16 + lc;
                yo[jj] = acc[i][j][q] + bv;
            }
        }
    }
}

// ---------------------------------------------------------------------------
extern "C" void kernel_launch(void* const* d_in, const int* in_sizes, int n_in,
                              void* d_out, int out_size, void* d_ws, size_t ws_size,
                              hipStream_t stream) {
    (void)in_sizes; (void)n_in; (void)out_size;
    const float* x  = (const float*)d_in[0];
    const float* A1 = (const float*)d_in[1];
    const float* A2 = (const float*)d_in[2];
    const float* W  = (const float*)d_in[3];
    const float* bs = (const float*)d_in[4];
    float* y = (float*)d_out;
    char* ws = (char*)d_ws;

    // workspace:
    //   [0, 8.39M)    Astack4 fp4 [8192][1024 B] (A*8192)
    //   [8.39M,+64K)  Wbf
    //   [CHUNK_OFF)   transient a1t4,a2t4 (2x2.1M) + a2sq bf16 (16.8M),
    //                 then per-chunk: XtT4 | X0 | Y
    const size_t CHUNK_OFF = 8454144;
    u8* astack4 = (u8*)ws;
    u16* wbf = (u16*)(ws + 8388608);
    u8* a1t4 = (u8*)(ws + CHUNK_OFF);
    u8* a2t4 = a1t4 + (size_t)2048 * 1024;
    u16* a2sq = (u16*)(a2t4 + (size_t)2048 * 1024);   // [4096][2048] bf16

    // per-chunk bytes: XtT4 Gb*786432 + X0 Gb*3145728 + Y Gb*12582912
    size_t avail = ws_size > CHUNK_OFF ? ws_size - CHUNK_OFF : 0;
    int Gb = 16;
    while (Gb > 1 && (size_t)Gb * 16515072 > avail) Gb >>= 1;
    int ldy = Gb * 768;
    u8* xtT4 = (u8*)(ws + CHUNK_OFF);
    u16* x0  = (u16*)(xtT4 + (size_t)Gb * 768 * 1024);
    u16* Yc  = x0 + (size_t)2048 * ldy;     // GEMM C = hops 1..4
    (void)Yc;

    cvt_w_kernel<<<80, 256, 0, stream>>>(W, wbf);
    cvt_a_kernel<<<2048, 256, 0, stream>>>(A1, A2, astack4, a1t4, a2t4);

    // A1^2, A2^2 in fp4 (dual launch); acc = A^2 * 2^26 -> bf16 * 2^-26
    gemm_f4_kernel<<<dim3(16, 16, 2), 256, 0, stream>>>(
        astack4, a1t4, a2sq,
        astack4 + (size_t)4096 * 1024, a2t4, a2sq + (size_t)2048 * 2048,
        1024, 1024, 1024, 2048, 1.f / 67108864.f);
    pack_a2_kernel<<<4096, 256, 0, stream>>>(a2sq, astack4);

    for (int b0 = 0; b0 < 16; b0 += Gb) {
        pack_x_kernel<<<Gb * 64, 256, 0, stream>>>(x, xtT4, x0, b0, ldy);
        gemm_f4_kernel<<<dim3(ldy / 128, 64, 1), 256, 0, stream>>>(
            astack4, xtT4, x0 + (size_t)2048 * ldy, astack4, xtT4, x0 + (size_t)2048 * ldy,
            1024, 1024, 1024, ldy, 1.f / 8192.f);
        conv_kernel<<<dim3(128, Gb), 256, 0, stream>>>(x0, wbf, bs, y, b0, ldy);
    }
}